// Round 3
// baseline (218.362 us; speedup 1.0000x reference)
//
#include <hip/hip_runtime.h>

typedef _Float16 h16;
typedef _Float16 f16x8 __attribute__((ext_vector_type(8)));
typedef _Float16 f16x4 __attribute__((ext_vector_type(4)));
typedef float f32x4 __attribute__((ext_vector_type(4)));

// ---------------- prep: weight transposes to [N][K] fp16 ----------------
// W1t[e][d] = gamma[d]*Wq[d][e] (e<1024) | Wkv[d][e-1024] (e in 1024..1151)
// Wot[o][i] = Wout[i][o]
__global__ __launch_bounds__(256) void prep_w(const float* __restrict__ Wq,
    const float* __restrict__ Wkv, const float* __restrict__ Wout,
    const float* __restrict__ gamma, h16* __restrict__ W1t, h16* __restrict__ Wot)
{
    __shared__ float ts[64][65];
    int bx = blockIdx.x, by = blockIdx.y;
    int c = threadIdx.x & 63, rc = threadIdx.x >> 6;
    const float* src; int ld, scol, drow0; h16* dst; bool useg = false;
    if (by < 16)      { src = Wq;   ld = 1024; scol = by*64;       dst = W1t; drow0 = scol;        useg = true; }
    else if (by < 18) { src = Wkv;  ld = 128;  scol = (by-16)*64;  dst = W1t; drow0 = 1024 + scol; }
    else              { src = Wout; ld = 1024; scol = (by-18)*64;  dst = Wot; drow0 = scol; }
#pragma unroll
    for (int i = 0; i < 16; ++i) {
        int r = rc*16 + i;
        float v = src[(size_t)(bx*64 + r)*ld + scol + c];
        if (useg) v *= gamma[bx*64 + r];
        ts[r][c] = v;
    }
    __syncthreads();
#pragma unroll
    for (int i = 0; i < 16; ++i) {
        int r = rc*16 + i;
        dst[(size_t)(drow0 + r)*1024 + bx*64 + c] = (h16)ts[c][r];
    }
}

// cq[e] = sum_d gamma[d]*Wq[d][e]
__global__ __launch_bounds__(256) void cq_k(const float* __restrict__ Wq,
    const float* __restrict__ gamma, float* __restrict__ cq)
{
    int e = blockIdx.x*256 + threadIdx.x;
    float s = 0.f;
    for (int d = 0; d < 1024; ++d) s += gamma[d] * Wq[(size_t)d*1024 + e];
    cq[e] = s;
}

// per-row mean + rsqrt(var+eps), and x -> fp16
__global__ __launch_bounds__(256) void stats_k(const float* __restrict__ x,
    float* __restrict__ mu, float* __restrict__ rr, h16* __restrict__ xh)
{
    int w = threadIdx.x >> 6, l = threadIdx.x & 63;
    int row = blockIdx.x*4 + w;
    const float* xr = x + (size_t)row*1024;
    float s = 0.f, ss = 0.f;
    float4 v[4];
#pragma unroll
    for (int i = 0; i < 4; ++i) {
        v[i] = *(const float4*)(xr + i*256 + l*4);
        s  += v[i].x + v[i].y + v[i].z + v[i].w;
        ss += v[i].x*v[i].x + v[i].y*v[i].y + v[i].z*v[i].z + v[i].w*v[i].w;
    }
#pragma unroll
    for (int m = 1; m < 64; m <<= 1) { s += __shfl_xor(s, m); ss += __shfl_xor(ss, m); }
    float m_ = s * (1.f/1024.f);
    float var = ss * (1.f/1024.f) - m_*m_;
    float r_ = rsqrtf(var + 1e-5f);
    if (l == 0) { mu[row] = m_; rr[row] = r_; }
    h16* xo = xh + (size_t)row*1024;
#pragma unroll
    for (int i = 0; i < 4; ++i) {
        f16x4 hv = { (h16)v[i].x, (h16)v[i].y, (h16)v[i].z, (h16)v[i].w };
        *(f16x4*)(xo + i*256 + l*4) = hv;
    }
}

// null kv rows (l2norm'd k * k_scale; raw v), zero the padding tail
__global__ __launch_bounds__(256) void null_k(const float* __restrict__ nkv,
    const float* __restrict__ kscale, h16* __restrict__ Kh, h16* __restrict__ Vth)
{
    int tid = threadIdx.x;
    if (tid < 128) {
        int t = tid >> 6, d = tid & 63;
        float kv = nkv[(0*2 + t)*64 + d];
        float ss = kv*kv;
#pragma unroll
        for (int m = 1; m < 64; m <<= 1) ss += __shfl_xor(ss, m);
        float inv = 1.f / fmaxf(sqrtf(ss), 1e-12f);
        h16 kvh = (h16)(kv * inv * kscale[d]);
        Kh[(size_t)(0*2112 + t)*64 + d] = kvh;
        Kh[(size_t)(1*2112 + t)*64 + d] = kvh;
        float nv = nkv[(2 + t)*64 + d];
        Vth[(size_t)(0*64 + d)*2112 + t] = (h16)nv;
        Vth[(size_t)(1*64 + d)*2112 + t] = (h16)nv;
    }
    for (int idx = tid; idx < 2*62*64; idx += 256) {
        int b = idx / (62*64), rem = idx % (62*64);
        int j = 2050 + rem/64, d = rem & 63;
        Kh[((size_t)b*2112 + j)*64 + d] = (h16)0.f;
        Vth[((size_t)b*64 + d)*2112 + j] = (h16)0.f;
    }
}

// ---------------- GEMM (128x128 tile, BK=64, 4 waves, gl_lds + XOR swizzle) ----------------
// MODE 0: A=xh[4096][1024], B=W1t[1152][1024]; epilogue: q (LN-fold + l2norm*q_scale) / k (l2norm*k_scale) / v (transposed store)
// MODE 1: A=Oh[4096][1024], B=Wot[1024][1024]; epilogue: fp32 store
template<int MODE>
__global__ __launch_bounds__(256) void gemm_k(
    const h16* __restrict__ A, const h16* __restrict__ B,
    const float* __restrict__ mu, const float* __restrict__ rr, const float* __restrict__ cq,
    const float* __restrict__ qscale, const float* __restrict__ kscale,
    h16* __restrict__ Qh, h16* __restrict__ Kh, h16* __restrict__ Vth, float* __restrict__ outp)
{
    __shared__ h16 As[128*64];
    __shared__ h16 Bs[128*64];
    int tid = threadIdx.x;
    int w = tid >> 6, l = tid & 63;
    int wm = w >> 1, wn = w & 1;
    int lq = l & 15, qq = l >> 4;
    int lr = l >> 3;                 // staging: row within 8-row chunk
    int cbs = ((l & 7)*16) ^ (lr << 4);  // pre-swizzled source byte col
    int arow0 = blockIdx.y*128, brow0 = blockIdx.x*128;
    const int K = 1024;
    f32x4 acc[4][4] = {};

    for (int kt = 0; kt < K; kt += 64) {
#pragma unroll
        for (int i = 0; i < 4; ++i) {
            int row = w*32 + i*8 + lr;
            const char* asrc = (const char*)(A + (size_t)(arow0 + row)*K + kt) + cbs;
            const char* bsrc = (const char*)(B + (size_t)(brow0 + row)*K + kt) + cbs;
            __builtin_amdgcn_global_load_lds(
                (const __attribute__((address_space(1))) unsigned int*)asrc,
                (__attribute__((address_space(3))) unsigned int*)(As + (w*32 + i*8)*64), 16, 0, 0);
            __builtin_amdgcn_global_load_lds(
                (const __attribute__((address_space(1))) unsigned int*)bsrc,
                (__attribute__((address_space(3))) unsigned int*)(Bs + (w*32 + i*8)*64), 16, 0, 0);
        }
        __syncthreads();
#pragma unroll
        for (int kc = 0; kc < 2; ++kc) {
            f16x8 af[4], bf[4];
#pragma unroll
            for (int mt = 0; mt < 4; ++mt) {
                int row = wm*64 + mt*16 + lq;
                int cb = (kc*64 + qq*16) ^ ((lq & 7) << 4);
                af[mt] = *(const f16x8*)((const char*)As + row*128 + cb);
            }
#pragma unroll
            for (int nt = 0; nt < 4; ++nt) {
                int row = wn*64 + nt*16 + lq;
                int cb = (kc*64 + qq*16) ^ ((lq & 7) << 4);
                bf[nt] = *(const f16x8*)((const char*)Bs + row*128 + cb);
            }
#pragma unroll
            for (int mt = 0; mt < 4; ++mt)
#pragma unroll
                for (int nt = 0; nt < 4; ++nt)
                    acc[mt][nt] = __builtin_amdgcn_mfma_f32_16x16x32_f16(af[mt], bf[nt], acc[mt][nt], 0, 0, 0);
        }
        __syncthreads();
    }

    int wrow0 = arow0 + wm*64, wcol0 = brow0 + wn*64;
    if (MODE == 1) {
#pragma unroll
        for (int mt = 0; mt < 4; ++mt)
#pragma unroll
            for (int nt = 0; nt < 4; ++nt)
#pragma unroll
                for (int i = 0; i < 4; ++i)
                    outp[(size_t)(wrow0 + mt*16 + qq*4 + i)*1024 + wcol0 + nt*16 + lq] = acc[mt][nt][i];
        return;
    }
    if (wcol0 < 1024) {
        float cqv[4], qs[4];
#pragma unroll
        for (int nt = 0; nt < 4; ++nt) {
            int col = wcol0 + nt*16 + lq;
            cqv[nt] = cq[col];
            qs[nt] = qscale[nt*16 + lq];
        }
#pragma unroll
        for (int mt = 0; mt < 4; ++mt) {
            float muv[4], rv[4], ssq[4], qv[4][4];
#pragma unroll
            for (int i = 0; i < 4; ++i) {
                int row = wrow0 + mt*16 + qq*4 + i;
                muv[i] = mu[row]; rv[i] = rr[row]; ssq[i] = 0.f;
            }
#pragma unroll
            for (int nt = 0; nt < 4; ++nt)
#pragma unroll
                for (int i = 0; i < 4; ++i) {
                    float q = rv[i]*(acc[mt][nt][i] - muv[i]*cqv[nt]);
                    qv[nt][i] = q; ssq[i] += q*q;
                }
#pragma unroll
            for (int i = 0; i < 4; ++i) {
                float s2 = ssq[i];
                s2 += __shfl_xor(s2, 1); s2 += __shfl_xor(s2, 2);
                s2 += __shfl_xor(s2, 4); s2 += __shfl_xor(s2, 8);
                ssq[i] = 1.f / fmaxf(sqrtf(s2), 1e-12f);
            }
#pragma unroll
            for (int nt = 0; nt < 4; ++nt)
#pragma unroll
                for (int i = 0; i < 4; ++i) {
                    int row = wrow0 + mt*16 + qq*4 + i;
                    Qh[(size_t)row*1024 + wcol0 + nt*16 + lq] = (h16)(qv[nt][i]*ssq[i]*qs[nt]);
                }
        }
    } else if (wcol0 == 1024) {  // k columns: l2norm * k_scale, store Kh[b][2+i][d]
        float ks[4];
#pragma unroll
        for (int nt = 0; nt < 4; ++nt) ks[nt] = kscale[nt*16 + lq];
#pragma unroll
        for (int mt = 0; mt < 4; ++mt) {
            float ssq[4] = {0.f, 0.f, 0.f, 0.f};
#pragma unroll
            for (int nt = 0; nt < 4; ++nt)
#pragma unroll
                for (int i = 0; i < 4; ++i) ssq[i] += acc[mt][nt][i]*acc[mt][nt][i];
#pragma unroll
            for (int i = 0; i < 4; ++i) {
                float s2 = ssq[i];
                s2 += __shfl_xor(s2, 1); s2 += __shfl_xor(s2, 2);
                s2 += __shfl_xor(s2, 4); s2 += __shfl_xor(s2, 8);
                ssq[i] = 1.f / fmaxf(sqrtf(s2), 1e-12f);
            }
#pragma unroll
            for (int nt = 0; nt < 4; ++nt)
#pragma unroll
                for (int i = 0; i < 4; ++i) {
                    int row = wrow0 + mt*16 + qq*4 + i;
                    int b = row >> 11, ii = row & 2047;
                    Kh[((size_t)b*2112 + 2 + ii)*64 + nt*16 + lq] = (h16)(acc[mt][nt][i]*ssq[i]*ks[nt]);
                }
        }
    } else {  // v columns: store transposed Vth[b][d][2+i]
#pragma unroll
        for (int mt = 0; mt < 4; ++mt)
#pragma unroll
            for (int nt = 0; nt < 4; ++nt)
#pragma unroll
                for (int i = 0; i < 4; ++i) {
                    int row = wrow0 + mt*16 + qq*4 + i;
                    int b = row >> 11, ii = row & 2047;
                    int d = nt*16 + lq;
                    Vth[((size_t)b*64 + d)*2112 + 2 + ii] = (h16)acc[mt][nt][i];
                }
    }
}

// ---------------- attention: swapped-operand flash, per-wave 32 q rows ----------------
__global__ __launch_bounds__(256) void attn_k(const h16* __restrict__ Qh,
    const h16* __restrict__ Kh, const h16* __restrict__ Vth, h16* __restrict__ Oh)
{
    __shared__ h16 Plds[4][32*72];
    int qt = blockIdx.x, bh = blockIdx.y;
    int b = bh >> 4, h = bh & 15;
    int tid = threadIdx.x, w = tid >> 6, l = tid & 63;
    int lq = l & 15, qq = l >> 4;
    int qstart = qt*128 + w*32;
    h16* P = &Plds[w][0];

    f16x8 qf[2][2];
#pragma unroll
    for (int nt = 0; nt < 2; ++nt)
#pragma unroll
        for (int kc = 0; kc < 2; ++kc)
            qf[nt][kc] = *(const f16x8*)(Qh + (size_t)(b*2048 + qstart + nt*16 + lq)*1024 + h*64 + kc*32 + qq*8);

    f32x4 oacc[4][2] = {};
    float mrun[2] = {-3e38f, -3e38f}, lrun[2] = {0.f, 0.f};
    int lastc = qstart + 33;
    if (qstart < 64 && lastc < 65) lastc = 65;   // non-causal prefix: rows<64 may attend cols<66
    if (lastc > 2049) lastc = 2049;
    int ntile = lastc/64 + 1;
    const h16* Kb = Kh + (size_t)b*2112*64;
    const h16* Vb = Vth + (size_t)b*64*2112;

    for (int t = 0; t < ntile; ++t) {
        int kv0 = t*64;
        f32x4 s[4][2] = {};
#pragma unroll
        for (int kc = 0; kc < 2; ++kc) {
            f16x8 kf[4];
#pragma unroll
            for (int mt = 0; mt < 4; ++mt)
                kf[mt] = *(const f16x8*)(Kb + (size_t)(kv0 + mt*16 + lq)*64 + kc*32 + qq*8);
#pragma unroll
            for (int mt = 0; mt < 4; ++mt)
#pragma unroll
                for (int nt = 0; nt < 2; ++nt)
                    s[mt][nt] = __builtin_amdgcn_mfma_f32_16x16x32_f16(kf[mt], qf[nt][kc], s[mt][nt], 0, 0, 0);
        }
        bool needmask = (kv0 + 63 > qstart + 2) || (t == 32);
#pragma unroll
        for (int mt = 0; mt < 4; ++mt)
#pragma unroll
            for (int nt = 0; nt < 2; ++nt)
#pragma unroll
                for (int i = 0; i < 4; ++i) {
                    float v = s[mt][nt][i]*8.f;
                    if (needmask) {
                        int kv = kv0 + mt*16 + qq*4 + i;
                        int qrow = qstart + nt*16 + lq;
                        bool ok = ((kv <= qrow + 2) || (qrow < 64 && kv < 66)) && (kv < 2050);
                        if (!ok) v = -3e38f;
                    }
                    s[mt][nt][i] = v;
                }
        // V frags (global, Vth is [d][j] so 16B contiguous)
        f16x8 vf[4][2];
#pragma unroll
        for (int dm = 0; dm < 4; ++dm)
#pragma unroll
            for (int kc = 0; kc < 2; ++kc)
                vf[dm][kc] = *(const f16x8*)(Vb + (size_t)(dm*16 + lq)*2112 + kv0 + kc*32 + qq*8);
#pragma unroll
        for (int nt = 0; nt < 2; ++nt) {
            float tm = -3e38f;
#pragma unroll
            for (int mt = 0; mt < 4; ++mt)
#pragma unroll
                for (int i = 0; i < 4; ++i) tm = fmaxf(tm, s[mt][nt][i]);
            tm = fmaxf(tm, __shfl_xor(tm, 16));
            tm = fmaxf(tm, __shfl_xor(tm, 32));
            float mn = fmaxf(mrun[nt], tm);
            float sc = __expf(mrun[nt] - mn);
            mrun[nt] = mn;
            float ps = 0.f;
#pragma unroll
            for (int mt = 0; mt < 4; ++mt)
#pragma unroll
                for (int i = 0; i < 4; ++i) {
                    float p = __expf(s[mt][nt][i] - mn);
                    s[mt][nt][i] = p; ps += p;
                }
            ps += __shfl_xor(ps, 16);
            ps += __shfl_xor(ps, 32);
            lrun[nt] = lrun[nt]*sc + ps;
#pragma unroll
            for (int dm = 0; dm < 4; ++dm) oacc[dm][nt] *= sc;
            // pack P (q-major [32][72], 4 consecutive kv per lane -> b64)
#pragma unroll
            for (int mt = 0; mt < 4; ++mt) {
                uint2 pk;
                pk.x = __builtin_bit_cast(unsigned int, __builtin_amdgcn_cvt_pkrtz(s[mt][nt][0], s[mt][nt][1]));
                pk.y = __builtin_bit_cast(unsigned int, __builtin_amdgcn_cvt_pkrtz(s[mt][nt][2], s[mt][nt][3]));
                *(uint2*)((char*)P + ((nt*16 + lq)*72 + mt*16 + qq*4)*2) = pk;
            }
        }
        // PV: O^T += V^T * P^T
#pragma unroll
        for (int nt = 0; nt < 2; ++nt)
#pragma unroll
            for (int kc = 0; kc < 2; ++kc) {
                f16x8 pf = *(const f16x8*)((const char*)P + ((nt*16 + lq)*72 + kc*32 + qq*8)*2);
#pragma unroll
                for (int dm = 0; dm < 4; ++dm)
                    oacc[dm][nt] = __builtin_amdgcn_mfma_f32_16x16x32_f16(vf[dm][kc], pf, oacc[dm][nt], 0, 0, 0);
            }
    }
#pragma unroll
    for (int nt = 0; nt < 2; ++nt) {
        float inv = 1.f / lrun[nt];
#pragma unroll
        for (int dm = 0; dm < 4; ++dm)
#pragma unroll
            for (int i = 0; i < 4; ++i) {
                int d = dm*16 + qq*4 + i;
                Oh[(size_t)(b*2048 + qstart + nt*16 + lq)*1024 + h*64 + d] = (h16)(oacc[dm][nt][i]*inv);
            }
    }
}

extern "C" void kernel_launch(void* const* d_in, const int* in_sizes, int n_in,
                              void* d_out, int out_size, void* d_ws, size_t ws_size,
                              hipStream_t stream)
{
    const float* x      = (const float*)d_in[0];
    const float* gamma  = (const float*)d_in[1];
    const float* Wq     = (const float*)d_in[2];
    const float* Wkv    = (const float*)d_in[3];
    const float* qscale = (const float*)d_in[4];
    const float* kscale = (const float*)d_in[5];
    const float* nkv    = (const float*)d_in[6];
    const float* Wout   = (const float*)d_in[7];
    float* out = (float*)d_out;
    char* ws = (char*)d_ws;

    h16* xh   = (h16*)(ws);                     // 4096*1024*2 = 8388608
    h16* Qh   = (h16*)(ws + 8388608);           // 8388608
    h16* Oh   = (h16*)(ws + 16777216);          // 8388608
    h16* W1t  = (h16*)(ws + 25165824);          // 1152*1024*2 = 2359296
    h16* Wot  = (h16*)(ws + 27525120);          // 1024*1024*2 = 2097152
    h16* Kh   = (h16*)(ws + 29622272);          // 2*2112*64*2 = 540672
    h16* Vth  = (h16*)(ws + 30162944);          // 540672
    float* cq = (float*)(ws + 30703616);        // 4096
    float* mu = (float*)(ws + 30707712);        // 16384
    float* rr = (float*)(ws + 30724096);        // 16384

    prep_w<<<dim3(16, 34), 256, 0, stream>>>(Wq, Wkv, Wout, gamma, W1t, Wot);
    cq_k<<<dim3(4), 256, 0, stream>>>(Wq, gamma, cq);
    stats_k<<<dim3(1024), 256, 0, stream>>>(x, mu, rr, xh);
    null_k<<<dim3(1), 256, 0, stream>>>(nkv, kscale, Kh, Vth);
    gemm_k<0><<<dim3(9, 32), 256, 0, stream>>>(xh, W1t, mu, rr, cq, qscale, kscale, Qh, Kh, Vth, out);
    attn_k<<<dim3(16, 32), 256, 0, stream>>>(Qh, Kh, Vth, Oh);
    gemm_k<1><<<dim3(8, 32), 256, 0, stream>>>(Oh, Wot, mu, rr, cq, qscale, kscale, Qh, Kh, Vth, out);
}

// Round 4
// 213.669 us; speedup vs baseline: 1.0220x; 1.0220x over previous
//
#include <hip/hip_runtime.h>

typedef _Float16 h16;
typedef _Float16 f16x8 __attribute__((ext_vector_type(8)));
typedef _Float16 f16x4 __attribute__((ext_vector_type(4)));
typedef float f32x4 __attribute__((ext_vector_type(4)));

// ---------------- prep: weight transposes to [N][K] fp16 ----------------
__global__ __launch_bounds__(256) void prep_w(const float* __restrict__ Wq,
    const float* __restrict__ Wkv, const float* __restrict__ Wout,
    const float* __restrict__ gamma, h16* __restrict__ W1t, h16* __restrict__ Wot)
{
    __shared__ float ts[64][65];
    int bx = blockIdx.x, by = blockIdx.y;
    int c = threadIdx.x & 63, rc = threadIdx.x >> 6;
    const float* src; int ld, scol, drow0; h16* dst; bool useg = false;
    if (by < 16)      { src = Wq;   ld = 1024; scol = by*64;       dst = W1t; drow0 = scol;        useg = true; }
    else if (by < 18) { src = Wkv;  ld = 128;  scol = (by-16)*64;  dst = W1t; drow0 = 1024 + scol; }
    else              { src = Wout; ld = 1024; scol = (by-18)*64;  dst = Wot; drow0 = scol; }
#pragma unroll
    for (int i = 0; i < 16; ++i) {
        int r = rc*16 + i;
        float v = src[(size_t)(bx*64 + r)*ld + scol + c];
        if (useg) v *= gamma[bx*64 + r];
        ts[r][c] = v;
    }
    __syncthreads();
#pragma unroll
    for (int i = 0; i < 16; ++i) {
        int r = rc*16 + i;
        dst[(size_t)(drow0 + r)*1024 + bx*64 + c] = (h16)ts[c][r];
    }
}

// cq[e] = sum_d gamma[d]*Wq[d][e]
__global__ __launch_bounds__(256) void cq_k(const float* __restrict__ Wq,
    const float* __restrict__ gamma, float* __restrict__ cq)
{
    int e = blockIdx.x*256 + threadIdx.x;
    float s = 0.f;
    for (int d = 0; d < 1024; ++d) s += gamma[d] * Wq[(size_t)d*1024 + e];
    cq[e] = s;
}

// per-row mean + rsqrt(var+eps), and x -> fp16
__global__ __launch_bounds__(256) void stats_k(const float* __restrict__ x,
    float* __restrict__ mu, float* __restrict__ rr, h16* __restrict__ xh)
{
    int w = threadIdx.x >> 6, l = threadIdx.x & 63;
    int row = blockIdx.x*4 + w;
    const float* xr = x + (size_t)row*1024;
    float s = 0.f, ss = 0.f;
    float4 v[4];
#pragma unroll
    for (int i = 0; i < 4; ++i) {
        v[i] = *(const float4*)(xr + i*256 + l*4);
        s  += v[i].x + v[i].y + v[i].z + v[i].w;
        ss += v[i].x*v[i].x + v[i].y*v[i].y + v[i].z*v[i].z + v[i].w*v[i].w;
    }
#pragma unroll
    for (int m = 1; m < 64; m <<= 1) { s += __shfl_xor(s, m); ss += __shfl_xor(ss, m); }
    float m_ = s * (1.f/1024.f);
    float var = ss * (1.f/1024.f) - m_*m_;
    float r_ = rsqrtf(var + 1e-5f);
    if (l == 0) { mu[row] = m_; rr[row] = r_; }
    h16* xo = xh + (size_t)row*1024;
#pragma unroll
    for (int i = 0; i < 4; ++i) {
        f16x4 hv = { (h16)v[i].x, (h16)v[i].y, (h16)v[i].z, (h16)v[i].w };
        *(f16x4*)(xo + i*256 + l*4) = hv;
    }
}

// null kv rows (l2norm'd k * k_scale; raw v), zero the padding tail
__global__ __launch_bounds__(256) void null_k(const float* __restrict__ nkv,
    const float* __restrict__ kscale, h16* __restrict__ Kh, h16* __restrict__ Vth)
{
    int tid = threadIdx.x;
    if (tid < 128) {
        int t = tid >> 6, d = tid & 63;
        float kv = nkv[(0*2 + t)*64 + d];
        float ss = kv*kv;
#pragma unroll
        for (int m = 1; m < 64; m <<= 1) ss += __shfl_xor(ss, m);
        float inv = 1.f / fmaxf(sqrtf(ss), 1e-12f);
        h16 kvh = (h16)(kv * inv * kscale[d]);
        Kh[(size_t)(0*2112 + t)*64 + d] = kvh;
        Kh[(size_t)(1*2112 + t)*64 + d] = kvh;
        float nv = nkv[(2 + t)*64 + d];
        Vth[(size_t)(0*64 + d)*2112 + t] = (h16)nv;
        Vth[(size_t)(1*64 + d)*2112 + t] = (h16)nv;
    }
    for (int idx = tid; idx < 2*62*64; idx += 256) {
        int b = idx / (62*64), rem = idx % (62*64);
        int j = 2050 + rem/64, d = rem & 63;
        Kh[((size_t)b*2112 + j)*64 + d] = (h16)0.f;
        Vth[((size_t)b*64 + d)*2112 + j] = (h16)0.f;
    }
}

// ---------------- GEMM (128x128 tile, BK=64, 4 waves, gl_lds + XOR swizzle) ----------------
template<int MODE>
__global__ __launch_bounds__(256) void gemm_k(
    const h16* __restrict__ A, const h16* __restrict__ B,
    const float* __restrict__ mu, const float* __restrict__ rr, const float* __restrict__ cq,
    const float* __restrict__ qscale, const float* __restrict__ kscale,
    h16* __restrict__ Qh, h16* __restrict__ Kh, h16* __restrict__ Vth, float* __restrict__ outp)
{
    __shared__ h16 As[128*64];
    __shared__ h16 Bs[128*64];
    int tid = threadIdx.x;
    int w = tid >> 6, l = tid & 63;
    int wm = w >> 1, wn = w & 1;
    int lq = l & 15, qq = l >> 4;
    int lr = l >> 3;
    int cbs = ((l & 7)*16) ^ (lr << 4);
    int arow0 = blockIdx.y*128, brow0 = blockIdx.x*128;
    const int K = 1024;
    f32x4 acc[4][4] = {};

    for (int kt = 0; kt < K; kt += 64) {
#pragma unroll
        for (int i = 0; i < 4; ++i) {
            int row = w*32 + i*8 + lr;
            const char* asrc = (const char*)(A + (size_t)(arow0 + row)*K + kt) + cbs;
            const char* bsrc = (const char*)(B + (size_t)(brow0 + row)*K + kt) + cbs;
            __builtin_amdgcn_global_load_lds(
                (const __attribute__((address_space(1))) unsigned int*)asrc,
                (__attribute__((address_space(3))) unsigned int*)(As + (w*32 + i*8)*64), 16, 0, 0);
            __builtin_amdgcn_global_load_lds(
                (const __attribute__((address_space(1))) unsigned int*)bsrc,
                (__attribute__((address_space(3))) unsigned int*)(Bs + (w*32 + i*8)*64), 16, 0, 0);
        }
        __syncthreads();
#pragma unroll
        for (int kc = 0; kc < 2; ++kc) {
            f16x8 af[4], bf[4];
#pragma unroll
            for (int mt = 0; mt < 4; ++mt) {
                int row = wm*64 + mt*16 + lq;
                int cb = (kc*64 + qq*16) ^ ((lq & 7) << 4);
                af[mt] = *(const f16x8*)((const char*)As + row*128 + cb);
            }
#pragma unroll
            for (int nt = 0; nt < 4; ++nt) {
                int row = wn*64 + nt*16 + lq;
                int cb = (kc*64 + qq*16) ^ ((lq & 7) << 4);
                bf[nt] = *(const f16x8*)((const char*)Bs + row*128 + cb);
            }
#pragma unroll
            for (int mt = 0; mt < 4; ++mt)
#pragma unroll
                for (int nt = 0; nt < 4; ++nt)
                    acc[mt][nt] = __builtin_amdgcn_mfma_f32_16x16x32_f16(af[mt], bf[nt], acc[mt][nt], 0, 0, 0);
        }
        __syncthreads();
    }

    int wrow0 = arow0 + wm*64, wcol0 = brow0 + wn*64;
    if (MODE == 1) {
#pragma unroll
        for (int mt = 0; mt < 4; ++mt)
#pragma unroll
            for (int nt = 0; nt < 4; ++nt)
#pragma unroll
                for (int i = 0; i < 4; ++i)
                    outp[(size_t)(wrow0 + mt*16 + qq*4 + i)*1024 + wcol0 + nt*16 + lq] = acc[mt][nt][i];
        return;
    }
    if (wcol0 < 1024) {
        float cqv[4], qs[4];
#pragma unroll
        for (int nt = 0; nt < 4; ++nt) {
            int col = wcol0 + nt*16 + lq;
            cqv[nt] = cq[col];
            qs[nt] = qscale[nt*16 + lq];
        }
#pragma unroll
        for (int mt = 0; mt < 4; ++mt) {
            float muv[4], rv[4], ssq[4], qv[4][4];
#pragma unroll
            for (int i = 0; i < 4; ++i) {
                int row = wrow0 + mt*16 + qq*4 + i;
                muv[i] = mu[row]; rv[i] = rr[row]; ssq[i] = 0.f;
            }
#pragma unroll
            for (int nt = 0; nt < 4; ++nt)
#pragma unroll
                for (int i = 0; i < 4; ++i) {
                    float q = rv[i]*(acc[mt][nt][i] - muv[i]*cqv[nt]);
                    qv[nt][i] = q; ssq[i] += q*q;
                }
#pragma unroll
            for (int i = 0; i < 4; ++i) {
                float s2 = ssq[i];
                s2 += __shfl_xor(s2, 1); s2 += __shfl_xor(s2, 2);
                s2 += __shfl_xor(s2, 4); s2 += __shfl_xor(s2, 8);
                ssq[i] = 1.f / fmaxf(sqrtf(s2), 1e-12f);
            }
#pragma unroll
            for (int nt = 0; nt < 4; ++nt)
#pragma unroll
                for (int i = 0; i < 4; ++i) {
                    int row = wrow0 + mt*16 + qq*4 + i;
                    Qh[(size_t)row*1024 + wcol0 + nt*16 + lq] = (h16)(qv[nt][i]*ssq[i]*qs[nt]);
                }
        }
    } else if (wcol0 == 1024) {
        float ks[4];
#pragma unroll
        for (int nt = 0; nt < 4; ++nt) ks[nt] = kscale[nt*16 + lq];
#pragma unroll
        for (int mt = 0; mt < 4; ++mt) {
            float ssq[4] = {0.f, 0.f, 0.f, 0.f};
#pragma unroll
            for (int nt = 0; nt < 4; ++nt)
#pragma unroll
                for (int i = 0; i < 4; ++i) ssq[i] += acc[mt][nt][i]*acc[mt][nt][i];
#pragma unroll
            for (int i = 0; i < 4; ++i) {
                float s2 = ssq[i];
                s2 += __shfl_xor(s2, 1); s2 += __shfl_xor(s2, 2);
                s2 += __shfl_xor(s2, 4); s2 += __shfl_xor(s2, 8);
                ssq[i] = 1.f / fmaxf(sqrtf(s2), 1e-12f);
            }
#pragma unroll
            for (int nt = 0; nt < 4; ++nt)
#pragma unroll
                for (int i = 0; i < 4; ++i) {
                    int row = wrow0 + mt*16 + qq*4 + i;
                    int b = row >> 11, ii = row & 2047;
                    Kh[((size_t)b*2112 + 2 + ii)*64 + nt*16 + lq] = (h16)(acc[mt][nt][i]*ssq[i]*ks[nt]);
                }
        }
    } else {
#pragma unroll
        for (int mt = 0; mt < 4; ++mt)
#pragma unroll
            for (int nt = 0; nt < 4; ++nt)
#pragma unroll
                for (int i = 0; i < 4; ++i) {
                    int row = wrow0 + mt*16 + qq*4 + i;
                    int b = row >> 11, ii = row & 2047;
                    int d = nt*16 + lq;
                    Vth[((size_t)b*64 + d)*2112 + 2 + ii] = (h16)acc[mt][nt][i];
                }
    }
}

// ---------------- attention: kv-split flash (block = 32 q rows, 4 waves split kv tiles) ----------------
__global__ __launch_bounds__(256) void attn_k(const h16* __restrict__ Qh,
    const h16* __restrict__ Kh, const h16* __restrict__ Vth, h16* __restrict__ Oh)
{
    // raw: during kv loop = per-wave P tiles (4 x 32x72 h16 = 18432 B);
    //      after loop      = Ob merge buffer (4x2x4x64x4 f32 = 32768 B)
    __shared__ char raw[32768];
    __shared__ float Ml[4][2][64][2];
    int qt = blockIdx.x, bh = blockIdx.y;
    int b = bh >> 4, h = bh & 15;
    int tid = threadIdx.x, w = tid >> 6, l = tid & 63;
    int lq = l & 15, qq = l >> 4;
    int qstart = qt*32;
    h16* P = (h16*)(raw + w*(32*72*2));

    f16x8 qf[2][2];
#pragma unroll
    for (int nt = 0; nt < 2; ++nt)
#pragma unroll
        for (int kc = 0; kc < 2; ++kc)
            qf[nt][kc] = *(const f16x8*)(Qh + (size_t)(b*2048 + qstart + nt*16 + lq)*1024 + h*64 + kc*32 + qq*8);

    f32x4 oacc[4][2] = {};
    float mrun[2] = {-3e38f, -3e38f}, lrun[2] = {0.f, 0.f};
    int lastc = qstart + 33;
    if (qstart < 64 && lastc < 65) lastc = 65;   // non-causal prefix: rows<64 may attend cols<66
    if (lastc > 2049) lastc = 2049;
    int ntile = lastc/64 + 1;
    const h16* Kb = Kh + (size_t)b*2112*64;
    const h16* Vb = Vth + (size_t)b*64*2112;

    for (int t = w; t < ntile; t += 4) {
        int kv0 = t*64;
        f32x4 s[4][2] = {};
#pragma unroll
        for (int kc = 0; kc < 2; ++kc) {
            f16x8 kf[4];
#pragma unroll
            for (int mt = 0; mt < 4; ++mt)
                kf[mt] = *(const f16x8*)(Kb + (size_t)(kv0 + mt*16 + lq)*64 + kc*32 + qq*8);
#pragma unroll
            for (int mt = 0; mt < 4; ++mt)
#pragma unroll
                for (int nt = 0; nt < 2; ++nt)
                    s[mt][nt] = __builtin_amdgcn_mfma_f32_16x16x32_f16(kf[mt], qf[nt][kc], s[mt][nt], 0, 0, 0);
        }
        bool needmask = (kv0 + 63 > qstart + 2) || (kv0 == 2048);
#pragma unroll
        for (int mt = 0; mt < 4; ++mt)
#pragma unroll
            for (int nt = 0; nt < 2; ++nt)
#pragma unroll
                for (int i = 0; i < 4; ++i) {
                    float v = s[mt][nt][i]*8.f;
                    if (needmask) {
                        int kv = kv0 + mt*16 + qq*4 + i;
                        int qrow = qstart + nt*16 + lq;
                        bool ok = ((kv <= qrow + 2) || (qrow < 64 && kv < 66)) && (kv < 2050);
                        if (!ok) v = -3e38f;
                    }
                    s[mt][nt][i] = v;
                }
        f16x8 vf[4][2];
#pragma unroll
        for (int dm = 0; dm < 4; ++dm)
#pragma unroll
            for (int kc = 0; kc < 2; ++kc)
                vf[dm][kc] = *(const f16x8*)(Vb + (size_t)(dm*16 + lq)*2112 + kv0 + kc*32 + qq*8);
#pragma unroll
        for (int nt = 0; nt < 2; ++nt) {
            float tm = -3e38f;
#pragma unroll
            for (int mt = 0; mt < 4; ++mt)
#pragma unroll
                for (int i = 0; i < 4; ++i) tm = fmaxf(tm, s[mt][nt][i]);
            tm = fmaxf(tm, __shfl_xor(tm, 16));
            tm = fmaxf(tm, __shfl_xor(tm, 32));
            float mn = fmaxf(mrun[nt], tm);
            float sc = __expf(mrun[nt] - mn);
            mrun[nt] = mn;
            float ps = 0.f;
#pragma unroll
            for (int mt = 0; mt < 4; ++mt)
#pragma unroll
                for (int i = 0; i < 4; ++i) {
                    float p = __expf(s[mt][nt][i] - mn);
                    s[mt][nt][i] = p; ps += p;
                }
            ps += __shfl_xor(ps, 16);
            ps += __shfl_xor(ps, 32);
            lrun[nt] = lrun[nt]*sc + ps;
#pragma unroll
            for (int dm = 0; dm < 4; ++dm) oacc[dm][nt] *= sc;
#pragma unroll
            for (int mt = 0; mt < 4; ++mt) {
                uint2 pk;
                pk.x = __builtin_bit_cast(unsigned int, __builtin_amdgcn_cvt_pkrtz(s[mt][nt][0], s[mt][nt][1]));
                pk.y = __builtin_bit_cast(unsigned int, __builtin_amdgcn_cvt_pkrtz(s[mt][nt][2], s[mt][nt][3]));
                *(uint2*)((char*)P + ((nt*16 + lq)*72 + mt*16 + qq*4)*2) = pk;
            }
        }
#pragma unroll
        for (int nt = 0; nt < 2; ++nt)
#pragma unroll
            for (int kc = 0; kc < 2; ++kc) {
                f16x8 pf = *(const f16x8*)((const char*)P + ((nt*16 + lq)*72 + kc*32 + qq*8)*2);
#pragma unroll
                for (int dm = 0; dm < 4; ++dm)
                    oacc[dm][nt] = __builtin_amdgcn_mfma_f32_16x16x32_f16(vf[dm][kc], pf, oacc[dm][nt], 0, 0, 0);
            }
    }

    // ---- merge the 4 per-wave partials ----
    __syncthreads();   // all waves done using P region before Ob overwrites it
    float* Ob = (float*)raw;   // [w][nt][dm][l][4]
#pragma unroll
    for (int nt = 0; nt < 2; ++nt) {
        Ml[w][nt][l][0] = mrun[nt];
        Ml[w][nt][l][1] = lrun[nt];
#pragma unroll
        for (int dm = 0; dm < 4; ++dm)
            *(f32x4*)(Ob + (((w*2 + nt)*4 + dm)*64 + l)*4) = oacc[dm][nt];
    }
    __syncthreads();
#pragma unroll
    for (int nt = 0; nt < 2; ++nt) {
        float m0 = Ml[0][nt][l][0], m1 = Ml[1][nt][l][0];
        float m2 = Ml[2][nt][l][0], m3 = Ml[3][nt][l][0];
        float M = fmaxf(fmaxf(m0, m1), fmaxf(m2, m3));
        float e0 = __expf(m0 - M), e1 = __expf(m1 - M);
        float e2 = __expf(m2 - M), e3 = __expf(m3 - M);
        float L = Ml[0][nt][l][1]*e0 + Ml[1][nt][l][1]*e1 + Ml[2][nt][l][1]*e2 + Ml[3][nt][l][1]*e3;
        f32x4 p0 = *(const f32x4*)(Ob + (((0*2 + nt)*4 + w)*64 + l)*4);
        f32x4 p1 = *(const f32x4*)(Ob + (((1*2 + nt)*4 + w)*64 + l)*4);
        f32x4 p2 = *(const f32x4*)(Ob + (((2*2 + nt)*4 + w)*64 + l)*4);
        f32x4 p3 = *(const f32x4*)(Ob + (((3*2 + nt)*4 + w)*64 + l)*4);
        float inv = 1.f / L;
        f16x4 ov;
#pragma unroll
        for (int i = 0; i < 4; ++i)
            ov[i] = (h16)((p0[i]*e0 + p1[i]*e1 + p2[i]*e2 + p3[i]*e3) * inv);
        // wave w owns d-quadrant dm == w
        *(f16x4*)(Oh + (size_t)(b*2048 + qstart + nt*16 + lq)*1024 + h*64 + w*16 + qq*4) = ov;
    }
}

extern "C" void kernel_launch(void* const* d_in, const int* in_sizes, int n_in,
                              void* d_out, int out_size, void* d_ws, size_t ws_size,
                              hipStream_t stream)
{
    const float* x      = (const float*)d_in[0];
    const float* gamma  = (const float*)d_in[1];
    const float* Wq     = (const float*)d_in[2];
    const float* Wkv    = (const float*)d_in[3];
    const float* qscale = (const float*)d_in[4];
    const float* kscale = (const float*)d_in[5];
    const float* nkv    = (const float*)d_in[6];
    const float* Wout   = (const float*)d_in[7];
    float* out = (float*)d_out;
    char* ws = (char*)d_ws;

    h16* xh   = (h16*)(ws);                     // 4096*1024*2 = 8388608
    h16* Qh   = (h16*)(ws + 8388608);           // 8388608
    h16* Oh   = (h16*)(ws + 16777216);          // 8388608
    h16* W1t  = (h16*)(ws + 25165824);          // 1152*1024*2 = 2359296
    h16* Wot  = (h16*)(ws + 27525120);          // 1024*1024*2 = 2097152
    h16* Kh   = (h16*)(ws + 29622272);          // 2*2112*64*2 = 540672
    h16* Vth  = (h16*)(ws + 30162944);          // 540672
    float* cq = (float*)(ws + 30703616);        // 4096
    float* mu = (float*)(ws + 30707712);        // 16384
    float* rr = (float*)(ws + 30724096);        // 16384

    prep_w<<<dim3(16, 34), 256, 0, stream>>>(Wq, Wkv, Wout, gamma, W1t, Wot);
    cq_k<<<dim3(4), 256, 0, stream>>>(Wq, gamma, cq);
    stats_k<<<dim3(1024), 256, 0, stream>>>(x, mu, rr, xh);
    null_k<<<dim3(1), 256, 0, stream>>>(nkv, kscale, Kh, Vth);
    gemm_k<0><<<dim3(9, 32), 256, 0, stream>>>(xh, W1t, mu, rr, cq, qscale, kscale, Qh, Kh, Vth, out);
    attn_k<<<dim3(64, 32), 256, 0, stream>>>(Qh, Kh, Vth, Oh);
    gemm_k<1><<<dim3(8, 32), 256, 0, stream>>>(Oh, Wot, mu, rr, cq, qscale, kscale, Qh, Kh, Vth, out);
}

// Round 5
// 133.292 us; speedup vs baseline: 1.6382x; 1.6030x over previous
//
#include <hip/hip_runtime.h>

typedef _Float16 h16;
typedef _Float16 f16x8 __attribute__((ext_vector_type(8)));
typedef _Float16 f16x4 __attribute__((ext_vector_type(4)));
typedef float f32x4 __attribute__((ext_vector_type(4)));

// ---------------- prep: weight transposes to [N][K] fp16, + cq colsum fused ----------------
__global__ __launch_bounds__(256) void prep_w(const float* __restrict__ Wq,
    const float* __restrict__ Wkv, const float* __restrict__ Wout,
    const float* __restrict__ gamma, h16* __restrict__ W1t, h16* __restrict__ Wot,
    float* __restrict__ cq)
{
    __shared__ float ts[64][65];
    int bx = blockIdx.x, by = blockIdx.y;
    int c = threadIdx.x & 63, rc = threadIdx.x >> 6;
    const float* src; int ld, scol, drow0; h16* dst; bool useg = false;
    if (by < 16)      { src = Wq;   ld = 1024; scol = by*64;       dst = W1t; drow0 = scol;        useg = true; }
    else if (by < 18) { src = Wkv;  ld = 128;  scol = (by-16)*64;  dst = W1t; drow0 = 1024 + scol; }
    else              { src = Wout; ld = 1024; scol = (by-18)*64;  dst = Wot; drow0 = scol; }
    float part = 0.f;
#pragma unroll
    for (int i = 0; i < 16; ++i) {
        int r = rc*16 + i;
        float v = src[(size_t)(bx*64 + r)*ld + scol + c];
        if (useg) v *= gamma[bx*64 + r];
        part += v;
        ts[r][c] = v;
    }
    if (useg) atomicAdd(&cq[scol + c], part);
    __syncthreads();
#pragma unroll
    for (int i = 0; i < 16; ++i) {
        int r = rc*16 + i;
        dst[(size_t)(drow0 + r)*1024 + bx*64 + c] = (h16)ts[c][r];
    }
}

// per-row mean + rsqrt(var+eps), and x -> fp16
__global__ __launch_bounds__(256) void stats_k(const float* __restrict__ x,
    float* __restrict__ mu, float* __restrict__ rr, h16* __restrict__ xh)
{
    int w = threadIdx.x >> 6, l = threadIdx.x & 63;
    int row = blockIdx.x*4 + w;
    const float* xr = x + (size_t)row*1024;
    float s = 0.f, ss = 0.f;
    float4 v[4];
#pragma unroll
    for (int i = 0; i < 4; ++i) {
        v[i] = *(const float4*)(xr + i*256 + l*4);
        s  += v[i].x + v[i].y + v[i].z + v[i].w;
        ss += v[i].x*v[i].x + v[i].y*v[i].y + v[i].z*v[i].z + v[i].w*v[i].w;
    }
#pragma unroll
    for (int m = 1; m < 64; m <<= 1) { s += __shfl_xor(s, m); ss += __shfl_xor(ss, m); }
    float m_ = s * (1.f/1024.f);
    float var = ss * (1.f/1024.f) - m_*m_;
    float r_ = rsqrtf(var + 1e-5f);
    if (l == 0) { mu[row] = m_; rr[row] = r_; }
    h16* xo = xh + (size_t)row*1024;
#pragma unroll
    for (int i = 0; i < 4; ++i) {
        f16x4 hv = { (h16)v[i].x, (h16)v[i].y, (h16)v[i].z, (h16)v[i].w };
        *(f16x4*)(xo + i*256 + l*4) = hv;
    }
}

// null kv rows (l2norm'd k * k_scale * 8; raw v), zero the padding tail
__global__ __launch_bounds__(256) void null_k(const float* __restrict__ nkv,
    const float* __restrict__ kscale, h16* __restrict__ Kh, h16* __restrict__ Vth)
{
    int tid = threadIdx.x;
    if (tid < 128) {
        int t = tid >> 6, d = tid & 63;
        float kv = nkv[(0*2 + t)*64 + d];
        float ss = kv*kv;
#pragma unroll
        for (int m = 1; m < 64; m <<= 1) ss += __shfl_xor(ss, m);
        float inv = 1.f / fmaxf(sqrtf(ss), 1e-12f);
        h16 kvh = (h16)(kv * inv * kscale[d] * 8.f);
        Kh[(size_t)(0*2112 + t)*64 + d] = kvh;
        Kh[(size_t)(1*2112 + t)*64 + d] = kvh;
        float nv = nkv[(2 + t)*64 + d];
        Vth[(size_t)(0*64 + d)*2112 + t] = (h16)nv;
        Vth[(size_t)(1*64 + d)*2112 + t] = (h16)nv;
    }
    for (int idx = tid; idx < 2*62*64; idx += 256) {
        int b = idx / (62*64), rem = idx % (62*64);
        int j = 2050 + rem/64, d = rem & 63;
        Kh[((size_t)b*2112 + j)*64 + d] = (h16)0.f;
        Vth[((size_t)b*64 + d)*2112 + j] = (h16)0.f;
    }
}

// ---------------- GEMM (128x128 tile, BK=64, 4 waves, gl_lds + XOR swizzle) ----------------
template<int MODE>
__global__ __launch_bounds__(256) void gemm_k(
    const h16* __restrict__ A, const h16* __restrict__ B,
    const float* __restrict__ mu, const float* __restrict__ rr, const float* __restrict__ cq,
    const float* __restrict__ qscale, const float* __restrict__ kscale,
    h16* __restrict__ Qh, h16* __restrict__ Kh, h16* __restrict__ Vth, float* __restrict__ outp)
{
    __shared__ h16 As[128*64];
    __shared__ h16 Bs[128*64];
    int tid = threadIdx.x;
    int w = tid >> 6, l = tid & 63;
    int wm = w >> 1, wn = w & 1;
    int lq = l & 15, qq = l >> 4;
    int lr = l >> 3;
    int cbs = ((l & 7)*16) ^ (lr << 4);
    int arow0 = blockIdx.y*128, brow0 = blockIdx.x*128;
    const int K = 1024;
    f32x4 acc[4][4] = {};

    for (int kt = 0; kt < K; kt += 64) {
#pragma unroll
        for (int i = 0; i < 4; ++i) {
            int row = w*32 + i*8 + lr;
            const char* asrc = (const char*)(A + (size_t)(arow0 + row)*K + kt) + cbs;
            const char* bsrc = (const char*)(B + (size_t)(brow0 + row)*K + kt) + cbs;
            __builtin_amdgcn_global_load_lds(
                (const __attribute__((address_space(1))) unsigned int*)asrc,
                (__attribute__((address_space(3))) unsigned int*)(As + (w*32 + i*8)*64), 16, 0, 0);
            __builtin_amdgcn_global_load_lds(
                (const __attribute__((address_space(1))) unsigned int*)bsrc,
                (__attribute__((address_space(3))) unsigned int*)(Bs + (w*32 + i*8)*64), 16, 0, 0);
        }
        __syncthreads();
#pragma unroll
        for (int kc = 0; kc < 2; ++kc) {
            f16x8 af[4], bf[4];
#pragma unroll
            for (int mt = 0; mt < 4; ++mt) {
                int row = wm*64 + mt*16 + lq;
                int cb = (kc*64 + qq*16) ^ ((lq & 7) << 4);
                af[mt] = *(const f16x8*)((const char*)As + row*128 + cb);
            }
#pragma unroll
            for (int nt = 0; nt < 4; ++nt) {
                int row = wn*64 + nt*16 + lq;
                int cb = (kc*64 + qq*16) ^ ((lq & 7) << 4);
                bf[nt] = *(const f16x8*)((const char*)Bs + row*128 + cb);
            }
#pragma unroll
            for (int mt = 0; mt < 4; ++mt)
#pragma unroll
                for (int nt = 0; nt < 4; ++nt)
                    acc[mt][nt] = __builtin_amdgcn_mfma_f32_16x16x32_f16(af[mt], bf[nt], acc[mt][nt], 0, 0, 0);
        }
        __syncthreads();
    }

    int wrow0 = arow0 + wm*64, wcol0 = brow0 + wn*64;
    if (MODE == 1) {
#pragma unroll
        for (int mt = 0; mt < 4; ++mt)
#pragma unroll
            for (int nt = 0; nt < 4; ++nt)
#pragma unroll
                for (int i = 0; i < 4; ++i)
                    outp[(size_t)(wrow0 + mt*16 + qq*4 + i)*1024 + wcol0 + nt*16 + lq] = acc[mt][nt][i];
        return;
    }
    if (wcol0 < 1024) {
        float cqv[4], qs[4];
#pragma unroll
        for (int nt = 0; nt < 4; ++nt) {
            int col = wcol0 + nt*16 + lq;
            cqv[nt] = cq[col];
            qs[nt] = qscale[nt*16 + lq];
        }
#pragma unroll
        for (int mt = 0; mt < 4; ++mt) {
            float muv[4], rv[4], ssq[4], qv[4][4];
#pragma unroll
            for (int i = 0; i < 4; ++i) {
                int row = wrow0 + mt*16 + qq*4 + i;
                muv[i] = mu[row]; rv[i] = rr[row]; ssq[i] = 0.f;
            }
#pragma unroll
            for (int nt = 0; nt < 4; ++nt)
#pragma unroll
                for (int i = 0; i < 4; ++i) {
                    float q = rv[i]*(acc[mt][nt][i] - muv[i]*cqv[nt]);
                    qv[nt][i] = q; ssq[i] += q*q;
                }
#pragma unroll
            for (int i = 0; i < 4; ++i) {
                float s2 = ssq[i];
                s2 += __shfl_xor(s2, 1); s2 += __shfl_xor(s2, 2);
                s2 += __shfl_xor(s2, 4); s2 += __shfl_xor(s2, 8);
                ssq[i] = 1.f / fmaxf(sqrtf(s2), 1e-12f);
            }
#pragma unroll
            for (int nt = 0; nt < 4; ++nt)
#pragma unroll
                for (int i = 0; i < 4; ++i) {
                    int row = wrow0 + mt*16 + qq*4 + i;
                    Qh[(size_t)row*1024 + wcol0 + nt*16 + lq] = (h16)(qv[nt][i]*ssq[i]*qs[nt]);
                }
        }
    } else if (wcol0 == 1024) {
        float ks[4];
#pragma unroll
        for (int nt = 0; nt < 4; ++nt) ks[nt] = kscale[nt*16 + lq] * 8.f;   // fold SCALE=8 into K
#pragma unroll
        for (int mt = 0; mt < 4; ++mt) {
            float ssq[4] = {0.f, 0.f, 0.f, 0.f};
#pragma unroll
            for (int nt = 0; nt < 4; ++nt)
#pragma unroll
                for (int i = 0; i < 4; ++i) ssq[i] += acc[mt][nt][i]*acc[mt][nt][i];
#pragma unroll
            for (int i = 0; i < 4; ++i) {
                float s2 = ssq[i];
                s2 += __shfl_xor(s2, 1); s2 += __shfl_xor(s2, 2);
                s2 += __shfl_xor(s2, 4); s2 += __shfl_xor(s2, 8);
                ssq[i] = 1.f / fmaxf(sqrtf(s2), 1e-12f);
            }
#pragma unroll
            for (int nt = 0; nt < 4; ++nt)
#pragma unroll
                for (int i = 0; i < 4; ++i) {
                    int row = wrow0 + mt*16 + qq*4 + i;
                    int b = row >> 11, ii = row & 2047;
                    Kh[((size_t)b*2112 + 2 + ii)*64 + nt*16 + lq] = (h16)(acc[mt][nt][i]*ssq[i]*ks[nt]);
                }
        }
    } else {
#pragma unroll
        for (int mt = 0; mt < 4; ++mt)
#pragma unroll
            for (int nt = 0; nt < 4; ++nt)
#pragma unroll
                for (int i = 0; i < 4; ++i) {
                    int row = wrow0 + mt*16 + qq*4 + i;
                    int b = row >> 11, ii = row & 2047;
                    int d = nt*16 + lq;
                    Vth[((size_t)b*64 + d)*2112 + 2 + ii] = (h16)acc[mt][nt][i];
                }
    }
}

// ---------------- attention: LDS-staged double-buffered flash ----------------
// block = 128 q rows (4 waves x 32 rows), K/V tiles staged via global_load_lds,
// XOR-swizzled LDS, counted vmcnt(4), raw s_barrier (no full drain).
__global__ __launch_bounds__(256, 2) void attn_k(const h16* __restrict__ Qh,
    const h16* __restrict__ Kh, const h16* __restrict__ Vth, h16* __restrict__ Oh)
{
    __shared__ h16 KVs[2][2][64*64];   // [buf][K|V][row*64+col]
    __shared__ h16 Ps[4][32*64];       // per-wave P, XOR-swizzled
    int id = blockIdx.x;
    int bh = id >> 4;
    int lo = id & 15;
    int qt = (id >> 8) ? (15 - lo) : lo;   // pair heavy+light blocks
    int b = bh >> 4, h = bh & 15;
    int tid = threadIdx.x, w = tid >> 6, l = tid & 63;
    int lq = l & 15, qq = l >> 4;
    int qstart = qt * 128;
    int q0w = qstart + w * 32;
    h16* P = &Ps[w][0];
    int xs = (lq & 7) << 4;
    int koff0 = (qq*16) ^ xs;
    int koff1 = (64 + qq*16) ^ xs;

    // Q fragments (once per block)
    f16x8 qf[2][2];
#pragma unroll
    for (int nt = 0; nt < 2; ++nt)
#pragma unroll
        for (int kc = 0; kc < 2; ++kc)
            qf[nt][kc] = *(const f16x8*)(Qh + (size_t)(b*2048 + q0w + nt*16 + lq)*1024 + h*64 + kc*32 + qq*8);

    // staging source bases (per lane, pre-swizzled)
    int cbs = ((tid & 7)*16) ^ (((tid >> 3) & 7) << 4);
    const char* ksrc = (const char*)(Kh + (size_t)b*2112*64) + (size_t)(tid >> 3)*128 + cbs;
    const char* vsrc = (const char*)(Vth + (size_t)b*64*2112) + (size_t)(tid >> 3)*4224 + cbs;

    f32x4 oacc[4][2] = {};
    float mrun[2] = {-3e38f, -3e38f}, lrun[2] = {0.f, 0.f};

    int lastc = qstart + 129;
    if (qstart < 64 && lastc < 65) lastc = 65;
    if (lastc > 2049) lastc = 2049;
    int ntile = lastc/64 + 1;

    auto STAGE = [&](int buf, int kv0) {
        const char* ks = ksrc + (size_t)kv0 * 128;
        const char* vs = vsrc + (size_t)kv0 * 2;
        __builtin_amdgcn_global_load_lds((const __attribute__((address_space(1))) unsigned int*)ks,
            (__attribute__((address_space(3))) unsigned int*)(&KVs[buf][0][(w*8)*64]), 16, 0, 0);
        __builtin_amdgcn_global_load_lds((const __attribute__((address_space(1))) unsigned int*)(ks + 32*128),
            (__attribute__((address_space(3))) unsigned int*)(&KVs[buf][0][(32 + w*8)*64]), 16, 0, 0);
        __builtin_amdgcn_global_load_lds((const __attribute__((address_space(1))) unsigned int*)vs,
            (__attribute__((address_space(3))) unsigned int*)(&KVs[buf][1][(w*8)*64]), 16, 0, 0);
        __builtin_amdgcn_global_load_lds((const __attribute__((address_space(1))) unsigned int*)(vs + (size_t)32*4224),
            (__attribute__((address_space(3))) unsigned int*)(&KVs[buf][1][(32 + w*8)*64]), 16, 0, 0);
    };

    STAGE(0, 0);
    int cur = 0;
    for (int t = 0; t < ntile; ++t) {
        int kv0 = t*64;
        int nxt = (t + 1 < ntile) ? t + 1 : t;
        STAGE(cur ^ 1, nxt*64);
        asm volatile("s_waitcnt vmcnt(4)" ::: "memory");
        __builtin_amdgcn_s_barrier();
        __builtin_amdgcn_sched_barrier(0);

        bool active = (kv0 <= q0w + 33) || (q0w < 64 && kv0 < 66);
        if (active) {
            const char* Kl = (const char*)&KVs[cur][0][0];
            const char* Vl = (const char*)&KVs[cur][1][0];
            f32x4 s[4][2] = {};
#pragma unroll
            for (int kc = 0; kc < 2; ++kc) {
                int ko = kc ? koff1 : koff0;
                f16x8 kf[4];
#pragma unroll
                for (int mt = 0; mt < 4; ++mt)
                    kf[mt] = *(const f16x8*)(Kl + (mt*16 + lq)*128 + ko);
#pragma unroll
                for (int mt = 0; mt < 4; ++mt)
#pragma unroll
                    for (int nt = 0; nt < 2; ++nt)
                        s[mt][nt] = __builtin_amdgcn_mfma_f32_16x16x32_f16(kf[mt], qf[nt][kc], s[mt][nt], 0, 0, 0);
            }
            bool needmask = (kv0 + 63 > q0w + 2) || (kv0 == 2048);
            if (needmask) {
#pragma unroll
                for (int mt = 0; mt < 4; ++mt)
#pragma unroll
                    for (int nt = 0; nt < 2; ++nt)
#pragma unroll
                        for (int i = 0; i < 4; ++i) {
                            int kv = kv0 + mt*16 + qq*4 + i;
                            int qrow = q0w + nt*16 + lq;
                            bool ok = ((kv <= qrow + 2) || (qrow < 64 && kv < 66)) && (kv < 2050);
                            if (!ok) s[mt][nt][i] = -3e38f;
                        }
            }
            // V fragments from LDS (issued early, consumed after softmax)
            f16x8 vf[4][2];
#pragma unroll
            for (int dm = 0; dm < 4; ++dm) {
                vf[dm][0] = *(const f16x8*)(Vl + (dm*16 + lq)*128 + koff0);
                vf[dm][1] = *(const f16x8*)(Vl + (dm*16 + lq)*128 + koff1);
            }
#pragma unroll
            for (int nt = 0; nt < 2; ++nt) {
                float tm = -3e38f;
#pragma unroll
                for (int mt = 0; mt < 4; ++mt)
#pragma unroll
                    for (int i = 0; i < 4; ++i) tm = fmaxf(tm, s[mt][nt][i]);
                tm = fmaxf(tm, __shfl_xor(tm, 16));
                tm = fmaxf(tm, __shfl_xor(tm, 32));
                float mn = fmaxf(mrun[nt], tm);
                float sc = __expf(mrun[nt] - mn);
                mrun[nt] = mn;
                float ps = 0.f;
#pragma unroll
                for (int mt = 0; mt < 4; ++mt)
#pragma unroll
                    for (int i = 0; i < 4; ++i) {
                        float p = __expf(s[mt][nt][i] - mn);
                        s[mt][nt][i] = p; ps += p;
                    }
                ps += __shfl_xor(ps, 16);
                ps += __shfl_xor(ps, 32);
                lrun[nt] = lrun[nt]*sc + ps;
#pragma unroll
                for (int dm = 0; dm < 4; ++dm) oacc[dm][nt] *= sc;
#pragma unroll
                for (int mt = 0; mt < 4; ++mt) {
                    uint2 pk;
                    pk.x = __builtin_bit_cast(unsigned int, __builtin_amdgcn_cvt_pkrtz(s[mt][nt][0], s[mt][nt][1]));
                    pk.y = __builtin_bit_cast(unsigned int, __builtin_amdgcn_cvt_pkrtz(s[mt][nt][2], s[mt][nt][3]));
                    *(uint2*)((char*)P + (nt*16 + lq)*128 + ((mt*32 + qq*8) ^ xs)) = pk;
                }
            }
#pragma unroll
            for (int nt = 0; nt < 2; ++nt)
#pragma unroll
                for (int kc = 0; kc < 2; ++kc) {
                    f16x8 pf = *(const f16x8*)((const char*)P + (nt*16 + lq)*128 + (kc ? koff1 : koff0));
#pragma unroll
                    for (int dm = 0; dm < 4; ++dm)
                        oacc[dm][nt] = __builtin_amdgcn_mfma_f32_16x16x32_f16(vf[dm][kc], pf, oacc[dm][nt], 0, 0, 0);
                }
        }
        __builtin_amdgcn_sched_barrier(0);
        __builtin_amdgcn_s_barrier();
        cur ^= 1;
    }
    asm volatile("s_waitcnt vmcnt(0)" ::: "memory");   // drain redundant last prefetch

#pragma unroll
    for (int nt = 0; nt < 2; ++nt) {
        float inv = 1.f / lrun[nt];
#pragma unroll
        for (int dm = 0; dm < 4; ++dm) {
            f16x4 ov;
#pragma unroll
            for (int i = 0; i < 4; ++i) ov[i] = (h16)(oacc[dm][nt][i]*inv);
            *(f16x4*)(Oh + (size_t)(b*2048 + q0w + nt*16 + lq)*1024 + h*64 + dm*16 + qq*4) = ov;
        }
    }
}

extern "C" void kernel_launch(void* const* d_in, const int* in_sizes, int n_in,
                              void* d_out, int out_size, void* d_ws, size_t ws_size,
                              hipStream_t stream)
{
    const float* x      = (const float*)d_in[0];
    const float* gamma  = (const float*)d_in[1];
    const float* Wq     = (const float*)d_in[2];
    const float* Wkv    = (const float*)d_in[3];
    const float* qscale = (const float*)d_in[4];
    const float* kscale = (const float*)d_in[5];
    const float* nkv    = (const float*)d_in[6];
    const float* Wout   = (const float*)d_in[7];
    float* out = (float*)d_out;
    char* ws = (char*)d_ws;

    h16* xh   = (h16*)(ws);                     // 8388608
    h16* Qh   = (h16*)(ws + 8388608);           // 8388608
    h16* Oh   = (h16*)(ws + 16777216);          // 8388608
    h16* W1t  = (h16*)(ws + 25165824);          // 2359296
    h16* Wot  = (h16*)(ws + 27525120);          // 2097152
    h16* Kh   = (h16*)(ws + 29622272);          // 540672
    h16* Vth  = (h16*)(ws + 30162944);          // 540672
    float* cq = (float*)(ws + 30703616);        // 4096
    float* mu = (float*)(ws + 30707712);        // 16384
    float* rr = (float*)(ws + 30724096);        // 16384

    hipMemsetAsync(cq, 0, 4096, stream);
    prep_w<<<dim3(16, 34), 256, 0, stream>>>(Wq, Wkv, Wout, gamma, W1t, Wot, cq);
    stats_k<<<dim3(1024), 256, 0, stream>>>(x, mu, rr, xh);
    null_k<<<dim3(1), 256, 0, stream>>>(nkv, kscale, Kh, Vth);
    gemm_k<0><<<dim3(9, 32), 256, 0, stream>>>(xh, W1t, mu, rr, cq, qscale, kscale, Qh, Kh, Vth, out);
    attn_k<<<dim3(512), 256, 0, stream>>>(Qh, Kh, Vth, Oh);
    gemm_k<1><<<dim3(8, 32), 256, 0, stream>>>(Oh, Wot, mu, rr, cq, qscale, kscale, Qh, Kh, Vth, out);
}

// Round 6
// 120.329 us; speedup vs baseline: 1.8147x; 1.1077x over previous
//
#include <hip/hip_runtime.h>

typedef _Float16 h16;
typedef _Float16 f16x8 __attribute__((ext_vector_type(8)));
typedef _Float16 f16x4 __attribute__((ext_vector_type(4)));
typedef float f32x4 __attribute__((ext_vector_type(4)));

#define KSCALE_FOLD 11.541560327111707f   // 8 * log2(e), folded into Kh

// ---------------- prep: weight transposes to [N][K] fp16, + cq colsum fused ----------------
__global__ __launch_bounds__(256) void prep_w(const float* __restrict__ Wq,
    const float* __restrict__ Wkv, const float* __restrict__ Wout,
    const float* __restrict__ gamma, h16* __restrict__ W1t, h16* __restrict__ Wot,
    float* __restrict__ cq)
{
    __shared__ float ts[64][65];
    int bx = blockIdx.x, by = blockIdx.y;
    int c = threadIdx.x & 63, rc = threadIdx.x >> 6;
    const float* src; int ld, scol, drow0; h16* dst; bool useg = false;
    if (by < 16)      { src = Wq;   ld = 1024; scol = by*64;       dst = W1t; drow0 = scol;        useg = true; }
    else if (by < 18) { src = Wkv;  ld = 128;  scol = (by-16)*64;  dst = W1t; drow0 = 1024 + scol; }
    else              { src = Wout; ld = 1024; scol = (by-18)*64;  dst = Wot; drow0 = scol; }
    float part = 0.f;
#pragma unroll
    for (int i = 0; i < 16; ++i) {
        int r = rc*16 + i;
        float v = src[(size_t)(bx*64 + r)*ld + scol + c];
        if (useg) v *= gamma[bx*64 + r];
        part += v;
        ts[r][c] = v;
    }
    if (useg) atomicAdd(&cq[scol + c], part);
    __syncthreads();
#pragma unroll
    for (int i = 0; i < 16; ++i) {
        int r = rc*16 + i;
        dst[(size_t)(drow0 + r)*1024 + bx*64 + c] = (h16)ts[c][r];
    }
}

// per-row mean + rsqrt(var+eps), and x -> fp16
__global__ __launch_bounds__(256) void stats_k(const float* __restrict__ x,
    float* __restrict__ mu, float* __restrict__ rr, h16* __restrict__ xh)
{
    int w = threadIdx.x >> 6, l = threadIdx.x & 63;
    int row = blockIdx.x*4 + w;
    const float* xr = x + (size_t)row*1024;
    float s = 0.f, ss = 0.f;
    float4 v[4];
#pragma unroll
    for (int i = 0; i < 4; ++i) {
        v[i] = *(const float4*)(xr + i*256 + l*4);
        s  += v[i].x + v[i].y + v[i].z + v[i].w;
        ss += v[i].x*v[i].x + v[i].y*v[i].y + v[i].z*v[i].z + v[i].w*v[i].w;
    }
#pragma unroll
    for (int m = 1; m < 64; m <<= 1) { s += __shfl_xor(s, m); ss += __shfl_xor(ss, m); }
    float m_ = s * (1.f/1024.f);
    float var = ss * (1.f/1024.f) - m_*m_;
    float r_ = rsqrtf(var + 1e-5f);
    if (l == 0) { mu[row] = m_; rr[row] = r_; }
    h16* xo = xh + (size_t)row*1024;
#pragma unroll
    for (int i = 0; i < 4; ++i) {
        f16x4 hv = { (h16)v[i].x, (h16)v[i].y, (h16)v[i].z, (h16)v[i].w };
        *(f16x4*)(xo + i*256 + l*4) = hv;
    }
}

// null kv rows (l2norm'd k * k_scale * 8*log2e; raw v), zero the padding tail
__global__ __launch_bounds__(256) void null_k(const float* __restrict__ nkv,
    const float* __restrict__ kscale, h16* __restrict__ Kh, h16* __restrict__ Vth)
{
    int tid = threadIdx.x;
    if (tid < 128) {
        int t = tid >> 6, d = tid & 63;
        float kv = nkv[(0*2 + t)*64 + d];
        float ss = kv*kv;
#pragma unroll
        for (int m = 1; m < 64; m <<= 1) ss += __shfl_xor(ss, m);
        float inv = 1.f / fmaxf(sqrtf(ss), 1e-12f);
        h16 kvh = (h16)(kv * inv * kscale[d] * KSCALE_FOLD);
        Kh[(size_t)(0*2112 + t)*64 + d] = kvh;
        Kh[(size_t)(1*2112 + t)*64 + d] = kvh;
        float nv = nkv[(2 + t)*64 + d];
        Vth[(size_t)(0*64 + d)*2112 + t] = (h16)nv;
        Vth[(size_t)(1*64 + d)*2112 + t] = (h16)nv;
    }
    for (int idx = tid; idx < 2*62*64; idx += 256) {
        int b = idx / (62*64), rem = idx % (62*64);
        int j = 2050 + rem/64, d = rem & 63;
        Kh[((size_t)b*2112 + j)*64 + d] = (h16)0.f;
        Vth[((size_t)b*64 + d)*2112 + j] = (h16)0.f;
    }
}

// ---------------- GEMM (128x128 tile, BK=64, 4 waves, gl_lds + XOR swizzle) ----------------
template<int MODE>
__global__ __launch_bounds__(256) void gemm_k(
    const h16* __restrict__ A, const h16* __restrict__ B,
    const float* __restrict__ mu, const float* __restrict__ rr, const float* __restrict__ cq,
    const float* __restrict__ qscale, const float* __restrict__ kscale,
    h16* __restrict__ Qh, h16* __restrict__ Kh, h16* __restrict__ Vth, float* __restrict__ outp)
{
    __shared__ h16 As[128*64];
    __shared__ h16 Bs[128*64];
    int tid = threadIdx.x;
    int w = tid >> 6, l = tid & 63;
    int wm = w >> 1, wn = w & 1;
    int lq = l & 15, qq = l >> 4;
    int lr = l >> 3;
    int cbs = ((l & 7)*16) ^ (lr << 4);
    int arow0 = blockIdx.y*128, brow0 = blockIdx.x*128;
    const int K = 1024;
    f32x4 acc[4][4] = {};

    for (int kt = 0; kt < K; kt += 64) {
#pragma unroll
        for (int i = 0; i < 4; ++i) {
            int row = w*32 + i*8 + lr;
            const char* asrc = (const char*)(A + (size_t)(arow0 + row)*K + kt) + cbs;
            const char* bsrc = (const char*)(B + (size_t)(brow0 + row)*K + kt) + cbs;
            __builtin_amdgcn_global_load_lds(
                (const __attribute__((address_space(1))) unsigned int*)asrc,
                (__attribute__((address_space(3))) unsigned int*)(As + (w*32 + i*8)*64), 16, 0, 0);
            __builtin_amdgcn_global_load_lds(
                (const __attribute__((address_space(1))) unsigned int*)bsrc,
                (__attribute__((address_space(3))) unsigned int*)(Bs + (w*32 + i*8)*64), 16, 0, 0);
        }
        __syncthreads();
#pragma unroll
        for (int kc = 0; kc < 2; ++kc) {
            f16x8 af[4], bf[4];
#pragma unroll
            for (int mt = 0; mt < 4; ++mt) {
                int row = wm*64 + mt*16 + lq;
                int cb = (kc*64 + qq*16) ^ ((lq & 7) << 4);
                af[mt] = *(const f16x8*)((const char*)As + row*128 + cb);
            }
#pragma unroll
            for (int nt = 0; nt < 4; ++nt) {
                int row = wn*64 + nt*16 + lq;
                int cb = (kc*64 + qq*16) ^ ((lq & 7) << 4);
                bf[nt] = *(const f16x8*)((const char*)Bs + row*128 + cb);
            }
#pragma unroll
            for (int mt = 0; mt < 4; ++mt)
#pragma unroll
                for (int nt = 0; nt < 4; ++nt)
                    acc[mt][nt] = __builtin_amdgcn_mfma_f32_16x16x32_f16(af[mt], bf[nt], acc[mt][nt], 0, 0, 0);
        }
        __syncthreads();
    }

    int wrow0 = arow0 + wm*64, wcol0 = brow0 + wn*64;
    if (MODE == 1) {
#pragma unroll
        for (int mt = 0; mt < 4; ++mt)
#pragma unroll
            for (int nt = 0; nt < 4; ++nt)
#pragma unroll
                for (int i = 0; i < 4; ++i)
                    outp[(size_t)(wrow0 + mt*16 + qq*4 + i)*1024 + wcol0 + nt*16 + lq] = acc[mt][nt][i];
        return;
    }
    if (wcol0 < 1024) {
        float cqv[4], qs[4];
#pragma unroll
        for (int nt = 0; nt < 4; ++nt) {
            int col = wcol0 + nt*16 + lq;
            cqv[nt] = cq[col];
            qs[nt] = qscale[nt*16 + lq];
        }
#pragma unroll
        for (int mt = 0; mt < 4; ++mt) {
            float muv[4], rv[4], ssq[4], qv[4][4];
#pragma unroll
            for (int i = 0; i < 4; ++i) {
                int row = wrow0 + mt*16 + qq*4 + i;
                muv[i] = mu[row]; rv[i] = rr[row]; ssq[i] = 0.f;
            }
#pragma unroll
            for (int nt = 0; nt < 4; ++nt)
#pragma unroll
                for (int i = 0; i < 4; ++i) {
                    float q = rv[i]*(acc[mt][nt][i] - muv[i]*cqv[nt]);
                    qv[nt][i] = q; ssq[i] += q*q;
                }
#pragma unroll
            for (int i = 0; i < 4; ++i) {
                float s2 = ssq[i];
                s2 += __shfl_xor(s2, 1); s2 += __shfl_xor(s2, 2);
                s2 += __shfl_xor(s2, 4); s2 += __shfl_xor(s2, 8);
                ssq[i] = 1.f / fmaxf(sqrtf(s2), 1e-12f);
            }
#pragma unroll
            for (int nt = 0; nt < 4; ++nt)
#pragma unroll
                for (int i = 0; i < 4; ++i) {
                    int row = wrow0 + mt*16 + qq*4 + i;
                    Qh[(size_t)row*1024 + wcol0 + nt*16 + lq] = (h16)(qv[nt][i]*ssq[i]*qs[nt]);
                }
        }
    } else if (wcol0 == 1024) {
        float ks[4];
#pragma unroll
        for (int nt = 0; nt < 4; ++nt) ks[nt] = kscale[nt*16 + lq] * KSCALE_FOLD;
#pragma unroll
        for (int mt = 0; mt < 4; ++mt) {
            float ssq[4] = {0.f, 0.f, 0.f, 0.f};
#pragma unroll
            for (int nt = 0; nt < 4; ++nt)
#pragma unroll
                for (int i = 0; i < 4; ++i) ssq[i] += acc[mt][nt][i]*acc[mt][nt][i];
#pragma unroll
            for (int i = 0; i < 4; ++i) {
                float s2 = ssq[i];
                s2 += __shfl_xor(s2, 1); s2 += __shfl_xor(s2, 2);
                s2 += __shfl_xor(s2, 4); s2 += __shfl_xor(s2, 8);
                ssq[i] = 1.f / fmaxf(sqrtf(s2), 1e-12f);
            }
#pragma unroll
            for (int nt = 0; nt < 4; ++nt)
#pragma unroll
                for (int i = 0; i < 4; ++i) {
                    int row = wrow0 + mt*16 + qq*4 + i;
                    int b = row >> 11, ii = row & 2047;
                    Kh[((size_t)b*2112 + 2 + ii)*64 + nt*16 + lq] = (h16)(acc[mt][nt][i]*ssq[i]*ks[nt]);
                }
        }
    } else {
#pragma unroll
        for (int mt = 0; mt < 4; ++mt)
#pragma unroll
            for (int nt = 0; nt < 4; ++nt)
#pragma unroll
                for (int i = 0; i < 4; ++i) {
                    int row = wrow0 + mt*16 + qq*4 + i;
                    int b = row >> 11, ii = row & 2047;
                    int d = nt*16 + lq;
                    Vth[((size_t)b*64 + d)*2112 + 2 + ii] = (h16)acc[mt][nt][i];
                }
    }
}

// ---------------- attention: staticmax exp2-domain flash ----------------
// block = 64 q rows (4 waves x 16 rows), K/V LDS-staged double-buffered,
// vmcnt(4) counted wait, no online max (|logit| bounded, 2^s fits fp16).
__global__ __launch_bounds__(256, 4) void attn_k(const h16* __restrict__ Qh,
    const h16* __restrict__ Kh, const h16* __restrict__ Vth, h16* __restrict__ Oh)
{
    __shared__ h16 KVs[2][2][64*64];   // [buf][K|V][row*64+col] swizzled
    __shared__ h16 Ps[4][16*64];       // per-wave P
    int id = blockIdx.x;
    int u = id >> 5;
    int qt = (u < 16) ? u : 47 - u;    // CU round-robin share {c,c+256,c+512,c+768} sums qt=62
    int bh = id & 31;
    int b = bh >> 4, h = bh & 15;
    int tid = threadIdx.x, w = tid >> 6, l = tid & 63;
    int lq = l & 15, qq = l >> 4;
    int qstart = qt * 64;
    int q0w = qstart + w * 16;
    h16* P = &Ps[w][0];
    int xs = (lq & 7) << 4;
    int koff0 = (qq*16) ^ xs;
    int koff1 = (64 + qq*16) ^ xs;

    // Q fragments
    f16x8 qf[2];
#pragma unroll
    for (int kc = 0; kc < 2; ++kc)
        qf[kc] = *(const f16x8*)(Qh + (size_t)(b*2048 + q0w + lq)*1024 + h*64 + kc*32 + qq*8);

    // mask threshold per lane (row = q0w + lq): allow kv <= thr
    int qrow = q0w + lq;
    int thr = qrow + 2;
    if (qrow < 64) thr = 65;
    if (thr > 2049) thr = 2049;

    // staging source bases (per lane, pre-swizzled)
    int cbs = ((tid & 7)*16) ^ (((tid >> 3) & 7) << 4);
    const char* ksrc = (const char*)(Kh + (size_t)b*2112*64) + (size_t)(tid >> 3)*128 + cbs;
    const char* vsrc = (const char*)(Vth + (size_t)b*64*2112) + (size_t)(tid >> 3)*4224 + cbs;

    f32x4 oacc[4] = {};
    float lrun = 0.f;

    int lastc = qstart + 65;
    if (lastc > 2049) lastc = 2049;
    int ntile = lastc/64 + 1;

    auto STAGE = [&](int buf, int kv0) {
        const char* ks = ksrc + (size_t)kv0 * 128;
        const char* vs = vsrc + (size_t)kv0 * 2;
        __builtin_amdgcn_global_load_lds((const __attribute__((address_space(1))) unsigned int*)ks,
            (__attribute__((address_space(3))) unsigned int*)(&KVs[buf][0][(w*8)*64]), 16, 0, 0);
        __builtin_amdgcn_global_load_lds((const __attribute__((address_space(1))) unsigned int*)(ks + 32*128),
            (__attribute__((address_space(3))) unsigned int*)(&KVs[buf][0][(32 + w*8)*64]), 16, 0, 0);
        __builtin_amdgcn_global_load_lds((const __attribute__((address_space(1))) unsigned int*)vs,
            (__attribute__((address_space(3))) unsigned int*)(&KVs[buf][1][(w*8)*64]), 16, 0, 0);
        __builtin_amdgcn_global_load_lds((const __attribute__((address_space(1))) unsigned int*)(vs + (size_t)32*4224),
            (__attribute__((address_space(3))) unsigned int*)(&KVs[buf][1][(32 + w*8)*64]), 16, 0, 0);
    };

    STAGE(0, 0);
    int cur = 0;
    for (int t = 0; t < ntile; ++t) {
        int kv0 = t*64;
        int nxt = (t + 1 < ntile) ? t + 1 : t;
        STAGE(cur ^ 1, nxt*64);
        asm volatile("s_waitcnt vmcnt(4)" ::: "memory");
        __builtin_amdgcn_s_barrier();
        __builtin_amdgcn_sched_barrier(0);

        bool active = (kv0 <= q0w + 17) || (q0w < 64 && kv0 < 66);
        if (active) {
            const char* Kl = (const char*)&KVs[cur][0][0];
            const char* Vl = (const char*)&KVs[cur][1][0];
            f32x4 s[4] = {};
#pragma unroll
            for (int kc = 0; kc < 2; ++kc) {
                int ko = kc ? koff1 : koff0;
                f16x8 kf[4];
#pragma unroll
                for (int mt = 0; mt < 4; ++mt)
                    kf[mt] = *(const f16x8*)(Kl + (mt*16 + lq)*128 + ko);
#pragma unroll
                for (int mt = 0; mt < 4; ++mt)
                    s[mt] = __builtin_amdgcn_mfma_f32_16x16x32_f16(kf[mt], qf[kc], s[mt], 0, 0, 0);
            }
            if (kv0 + 63 > q0w + 2) {   // mask needed
#pragma unroll
                for (int mt = 0; mt < 4; ++mt)
#pragma unroll
                    for (int i = 0; i < 4; ++i) {
                        int kv = kv0 + mt*16 + qq*4 + i;
                        if (kv > thr) s[mt][i] = -__builtin_inff();
                    }
            }
            // P = 2^s (no max subtraction; normalization cancels in O = oacc/l)
            float ps = 0.f;
#pragma unroll
            for (int mt = 0; mt < 4; ++mt)
#pragma unroll
                for (int i = 0; i < 4; ++i) {
                    float p = exp2f(s[mt][i]);
                    s[mt][i] = p; ps += p;
                }
            ps += __shfl_xor(ps, 16);
            ps += __shfl_xor(ps, 32);
            lrun += ps;
#pragma unroll
            for (int mt = 0; mt < 4; ++mt) {
                uint2 pk;
                pk.x = __builtin_bit_cast(unsigned int, __builtin_amdgcn_cvt_pkrtz(s[mt][0], s[mt][1]));
                pk.y = __builtin_bit_cast(unsigned int, __builtin_amdgcn_cvt_pkrtz(s[mt][2], s[mt][3]));
                *(uint2*)((char*)P + lq*128 + ((mt*32 + qq*8) ^ xs)) = pk;
            }
#pragma unroll
            for (int kc = 0; kc < 2; ++kc) {
                int ko = kc ? koff1 : koff0;
                f16x8 vf[4];
#pragma unroll
                for (int dm = 0; dm < 4; ++dm)
                    vf[dm] = *(const f16x8*)(Vl + (dm*16 + lq)*128 + ko);
                f16x8 pf = *(const f16x8*)((const char*)P + lq*128 + ko);
#pragma unroll
                for (int dm = 0; dm < 4; ++dm)
                    oacc[dm] = __builtin_amdgcn_mfma_f32_16x16x32_f16(vf[dm], pf, oacc[dm], 0, 0, 0);
            }
        }
        __builtin_amdgcn_sched_barrier(0);
        __builtin_amdgcn_s_barrier();
        cur ^= 1;
    }
    asm volatile("s_waitcnt vmcnt(0)" ::: "memory");

    float inv = 1.f / lrun;
#pragma unroll
    for (int dm = 0; dm < 4; ++dm) {
        f16x4 ov;
#pragma unroll
        for (int i = 0; i < 4; ++i) ov[i] = (h16)(oacc[dm][i]*inv);
        *(f16x4*)(Oh + (size_t)(b*2048 + q0w + lq)*1024 + h*64 + dm*16 + qq*4) = ov;
    }
}

extern "C" void kernel_launch(void* const* d_in, const int* in_sizes, int n_in,
                              void* d_out, int out_size, void* d_ws, size_t ws_size,
                              hipStream_t stream)
{
    const float* x      = (const float*)d_in[0];
    const float* gamma  = (const float*)d_in[1];
    const float* Wq     = (const float*)d_in[2];
    const float* Wkv    = (const float*)d_in[3];
    const float* qscale = (const float*)d_in[4];
    const float* kscale = (const float*)d_in[5];
    const float* nkv    = (const float*)d_in[6];
    const float* Wout   = (const float*)d_in[7];
    float* out = (float*)d_out;
    char* ws = (char*)d_ws;

    h16* xh   = (h16*)(ws);                     // 8388608
    h16* Qh   = (h16*)(ws + 8388608);           // 8388608
    h16* Oh   = (h16*)(ws + 16777216);          // 8388608
    h16* W1t  = (h16*)(ws + 25165824);          // 2359296
    h16* Wot  = (h16*)(ws + 27525120);          // 2097152
    h16* Kh   = (h16*)(ws + 29622272);          // 540672
    h16* Vth  = (h16*)(ws + 30162944);          // 540672
    float* cq = (float*)(ws + 30703616);        // 4096
    float* mu = (float*)(ws + 30707712);        // 16384
    float* rr = (float*)(ws + 30724096);        // 16384

    hipMemsetAsync(cq, 0, 4096, stream);
    prep_w<<<dim3(16, 34), 256, 0, stream>>>(Wq, Wkv, Wout, gamma, W1t, Wot, cq);
    stats_k<<<dim3(1024), 256, 0, stream>>>(x, mu, rr, xh);
    null_k<<<dim3(1), 256, 0, stream>>>(nkv, kscale, Kh, Vth);
    gemm_k<0><<<dim3(9, 32), 256, 0, stream>>>(xh, W1t, mu, rr, cq, qscale, kscale, Qh, Kh, Vth, out);
    attn_k<<<dim3(1024), 256, 0, stream>>>(Qh, Kh, Vth, Oh);
    gemm_k<1><<<dim3(8, 32), 256, 0, stream>>>(Oh, Wot, mu, rr, cq, qscale, kscale, Qh, Kh, Vth, out);
}

// Round 7
// 114.810 us; speedup vs baseline: 1.9019x; 1.0481x over previous
//
#include <hip/hip_runtime.h>

typedef _Float16 h16;
typedef _Float16 f16x8 __attribute__((ext_vector_type(8)));
typedef _Float16 f16x4 __attribute__((ext_vector_type(4)));
typedef float f32x4 __attribute__((ext_vector_type(4)));

#define KSCALE_FOLD 11.541560327111707f   // 8 * log2(e), folded into Kh

// ---------------- prep: weight transposes to [N][K] fp16, + cq colsum fused ----------------
__global__ __launch_bounds__(256) void prep_w(const float* __restrict__ Wq,
    const float* __restrict__ Wkv, const float* __restrict__ Wout,
    const float* __restrict__ gamma, h16* __restrict__ W1t, h16* __restrict__ Wot,
    float* __restrict__ cq)
{
    __shared__ float ts[64][65];
    int bx = blockIdx.x, by = blockIdx.y;
    int c = threadIdx.x & 63, rc = threadIdx.x >> 6;
    const float* src; int ld, scol, drow0; h16* dst; bool useg = false;
    if (by < 16)      { src = Wq;   ld = 1024; scol = by*64;       dst = W1t; drow0 = scol;        useg = true; }
    else if (by < 18) { src = Wkv;  ld = 128;  scol = (by-16)*64;  dst = W1t; drow0 = 1024 + scol; }
    else              { src = Wout; ld = 1024; scol = (by-18)*64;  dst = Wot; drow0 = scol; }
    float part = 0.f;
#pragma unroll
    for (int i = 0; i < 16; ++i) {
        int r = rc*16 + i;
        float v = src[(size_t)(bx*64 + r)*ld + scol + c];
        if (useg) v *= gamma[bx*64 + r];
        part += v;
        ts[r][c] = v;
    }
    if (useg) atomicAdd(&cq[scol + c], part);
    __syncthreads();
#pragma unroll
    for (int i = 0; i < 16; ++i) {
        int r = rc*16 + i;
        dst[(size_t)(drow0 + r)*1024 + bx*64 + c] = (h16)ts[c][r];
    }
}

// per-row mean + rsqrt(var+eps), and x -> fp16
__global__ __launch_bounds__(256) void stats_k(const float* __restrict__ x,
    float* __restrict__ mu, float* __restrict__ rr, h16* __restrict__ xh)
{
    int w = threadIdx.x >> 6, l = threadIdx.x & 63;
    int row = blockIdx.x*4 + w;
    const float* xr = x + (size_t)row*1024;
    float s = 0.f, ss = 0.f;
    float4 v[4];
#pragma unroll
    for (int i = 0; i < 4; ++i) {
        v[i] = *(const float4*)(xr + i*256 + l*4);
        s  += v[i].x + v[i].y + v[i].z + v[i].w;
        ss += v[i].x*v[i].x + v[i].y*v[i].y + v[i].z*v[i].z + v[i].w*v[i].w;
    }
#pragma unroll
    for (int m = 1; m < 64; m <<= 1) { s += __shfl_xor(s, m); ss += __shfl_xor(ss, m); }
    float m_ = s * (1.f/1024.f);
    float var = ss * (1.f/1024.f) - m_*m_;
    float r_ = rsqrtf(var + 1e-5f);
    if (l == 0) { mu[row] = m_; rr[row] = r_; }
    h16* xo = xh + (size_t)row*1024;
#pragma unroll
    for (int i = 0; i < 4; ++i) {
        f16x4 hv = { (h16)v[i].x, (h16)v[i].y, (h16)v[i].z, (h16)v[i].w };
        *(f16x4*)(xo + i*256 + l*4) = hv;
    }
}

// null kv rows (l2norm'd k * k_scale * 8*log2e; raw v), zero the padding tail
__global__ __launch_bounds__(256) void null_k(const float* __restrict__ nkv,
    const float* __restrict__ kscale, h16* __restrict__ Kh, h16* __restrict__ Vth)
{
    int tid = threadIdx.x;
    if (blockIdx.x == 0 && tid < 128) {
        int t = tid >> 6, d = tid & 63;
        float kv = nkv[(0*2 + t)*64 + d];
        float ss = kv*kv;
#pragma unroll
        for (int m = 1; m < 64; m <<= 1) ss += __shfl_xor(ss, m);
        float inv = 1.f / fmaxf(sqrtf(ss), 1e-12f);
        h16 kvh = (h16)(kv * inv * kscale[d] * KSCALE_FOLD);
        Kh[(size_t)(0*2112 + t)*64 + d] = kvh;
        Kh[(size_t)(1*2112 + t)*64 + d] = kvh;
        float nv = nkv[(2 + t)*64 + d];
        Vth[(size_t)(0*64 + d)*2112 + t] = (h16)nv;
        Vth[(size_t)(1*64 + d)*2112 + t] = (h16)nv;
    }
    for (int idx = blockIdx.x*256 + tid; idx < 2*62*64; idx += 2048) {
        int b = idx / (62*64), rem = idx % (62*64);
        int j = 2050 + rem/64, d = rem & 63;
        Kh[((size_t)b*2112 + j)*64 + d] = (h16)0.f;
        Vth[((size_t)b*64 + d)*2112 + j] = (h16)0.f;
    }
}

// ---------------- GEMM (128x128 tile, BK=64, 4 waves, dbuf gl_lds + XOR swizzle) ----------------
template<int MODE>
__global__ __launch_bounds__(256) void gemm_k(
    const h16* __restrict__ A, const h16* __restrict__ B,
    const float* __restrict__ mu, const float* __restrict__ rr, const float* __restrict__ cq,
    const float* __restrict__ qscale, const float* __restrict__ kscale,
    h16* __restrict__ Qh, h16* __restrict__ Kh, h16* __restrict__ Vth, float* __restrict__ outp)
{
    __shared__ h16 As[2][128*64];
    __shared__ h16 Bs[2][128*64];
    int tid = threadIdx.x;
    int w = tid >> 6, l = tid & 63;
    int wm = w >> 1, wn = w & 1;
    int lq = l & 15, qq = l >> 4;
    int lr = l >> 3;
    int cbs = ((l & 7)*16) ^ (lr << 4);
    int arow0 = blockIdx.y*128, brow0 = blockIdx.x*128;
    const int K = 1024;
    f32x4 acc[4][4] = {};

    auto STAGE = [&](int buf, int kt) {
#pragma unroll
        for (int i = 0; i < 4; ++i) {
            int row = w*32 + i*8 + lr;
            const char* asrc = (const char*)(A + (size_t)(arow0 + row)*K + kt) + cbs;
            const char* bsrc = (const char*)(B + (size_t)(brow0 + row)*K + kt) + cbs;
            __builtin_amdgcn_global_load_lds(
                (const __attribute__((address_space(1))) unsigned int*)asrc,
                (__attribute__((address_space(3))) unsigned int*)(&As[buf][(w*32 + i*8)*64]), 16, 0, 0);
            __builtin_amdgcn_global_load_lds(
                (const __attribute__((address_space(1))) unsigned int*)bsrc,
                (__attribute__((address_space(3))) unsigned int*)(&Bs[buf][(w*32 + i*8)*64]), 16, 0, 0);
        }
    };

    STAGE(0, 0);
    int cur = 0;
    for (int kt = 0; kt < K; kt += 64) {
        int nkt = (kt + 64 < K) ? kt + 64 : kt;
        STAGE(cur ^ 1, nkt);
        asm volatile("s_waitcnt vmcnt(8)" ::: "memory");
        __builtin_amdgcn_s_barrier();
        __builtin_amdgcn_sched_barrier(0);
        const char* Ab = (const char*)&As[cur][0];
        const char* Bb = (const char*)&Bs[cur][0];
#pragma unroll
        for (int kc = 0; kc < 2; ++kc) {
            f16x8 af[4], bf[4];
#pragma unroll
            for (int mt = 0; mt < 4; ++mt) {
                int row = wm*64 + mt*16 + lq;
                int cb = (kc*64 + qq*16) ^ ((lq & 7) << 4);
                af[mt] = *(const f16x8*)(Ab + row*128 + cb);
            }
#pragma unroll
            for (int nt = 0; nt < 4; ++nt) {
                int row = wn*64 + nt*16 + lq;
                int cb = (kc*64 + qq*16) ^ ((lq & 7) << 4);
                bf[nt] = *(const f16x8*)(Bb + row*128 + cb);
            }
#pragma unroll
            for (int mt = 0; mt < 4; ++mt)
#pragma unroll
                for (int nt = 0; nt < 4; ++nt)
                    acc[mt][nt] = __builtin_amdgcn_mfma_f32_16x16x32_f16(af[mt], bf[nt], acc[mt][nt], 0, 0, 0);
        }
        __builtin_amdgcn_sched_barrier(0);
        __builtin_amdgcn_s_barrier();
        cur ^= 1;
    }
    asm volatile("s_waitcnt vmcnt(0)" ::: "memory");

    int wrow0 = arow0 + wm*64, wcol0 = brow0 + wn*64;
    if (MODE == 1) {
#pragma unroll
        for (int mt = 0; mt < 4; ++mt)
#pragma unroll
            for (int nt = 0; nt < 4; ++nt)
#pragma unroll
                for (int i = 0; i < 4; ++i)
                    outp[(size_t)(wrow0 + mt*16 + qq*4 + i)*1024 + wcol0 + nt*16 + lq] = acc[mt][nt][i];
        return;
    }
    if (wcol0 < 1024) {
        float cqv[4], qs[4];
#pragma unroll
        for (int nt = 0; nt < 4; ++nt) {
            int col = wcol0 + nt*16 + lq;
            cqv[nt] = cq[col];
            qs[nt] = qscale[nt*16 + lq];
        }
#pragma unroll
        for (int mt = 0; mt < 4; ++mt) {
            float muv[4], rv[4], ssq[4], qv[4][4];
#pragma unroll
            for (int i = 0; i < 4; ++i) {
                int row = wrow0 + mt*16 + qq*4 + i;
                muv[i] = mu[row]; rv[i] = rr[row]; ssq[i] = 0.f;
            }
#pragma unroll
            for (int nt = 0; nt < 4; ++nt)
#pragma unroll
                for (int i = 0; i < 4; ++i) {
                    float q = rv[i]*(acc[mt][nt][i] - muv[i]*cqv[nt]);
                    qv[nt][i] = q; ssq[i] += q*q;
                }
#pragma unroll
            for (int i = 0; i < 4; ++i) {
                float s2 = ssq[i];
                s2 += __shfl_xor(s2, 1); s2 += __shfl_xor(s2, 2);
                s2 += __shfl_xor(s2, 4); s2 += __shfl_xor(s2, 8);
                ssq[i] = 1.f / fmaxf(sqrtf(s2), 1e-12f);
            }
#pragma unroll
            for (int nt = 0; nt < 4; ++nt)
#pragma unroll
                for (int i = 0; i < 4; ++i) {
                    int row = wrow0 + mt*16 + qq*4 + i;
                    Qh[(size_t)row*1024 + wcol0 + nt*16 + lq] = (h16)(qv[nt][i]*ssq[i]*qs[nt]);
                }
        }
    } else if (wcol0 == 1024) {
        float ks[4];
#pragma unroll
        for (int nt = 0; nt < 4; ++nt) ks[nt] = kscale[nt*16 + lq] * KSCALE_FOLD;
#pragma unroll
        for (int mt = 0; mt < 4; ++mt) {
            float ssq[4] = {0.f, 0.f, 0.f, 0.f};
#pragma unroll
            for (int nt = 0; nt < 4; ++nt)
#pragma unroll
                for (int i = 0; i < 4; ++i) ssq[i] += acc[mt][nt][i]*acc[mt][nt][i];
#pragma unroll
            for (int i = 0; i < 4; ++i) {
                float s2 = ssq[i];
                s2 += __shfl_xor(s2, 1); s2 += __shfl_xor(s2, 2);
                s2 += __shfl_xor(s2, 4); s2 += __shfl_xor(s2, 8);
                ssq[i] = 1.f / fmaxf(sqrtf(s2), 1e-12f);
            }
#pragma unroll
            for (int nt = 0; nt < 4; ++nt)
#pragma unroll
                for (int i = 0; i < 4; ++i) {
                    int row = wrow0 + mt*16 + qq*4 + i;
                    int b = row >> 11, ii = row & 2047;
                    Kh[((size_t)b*2112 + 2 + ii)*64 + nt*16 + lq] = (h16)(acc[mt][nt][i]*ssq[i]*ks[nt]);
                }
        }
    } else {
#pragma unroll
        for (int mt = 0; mt < 4; ++mt)
#pragma unroll
            for (int nt = 0; nt < 4; ++nt)
#pragma unroll
                for (int i = 0; i < 4; ++i) {
                    int row = wrow0 + mt*16 + qq*4 + i;
                    int b = row >> 11, ii = row & 2047;
                    int d = nt*16 + lq;
                    Vth[((size_t)b*64 + d)*2112 + 2 + ii] = (h16)acc[mt][nt][i];
                }
    }
}

// ---------------- attention: 8-wave kv-split staticmax exp2 flash ----------------
// block = 64 q rows; waves w and w+4 share rows, split each kv tile into halves.
// Additive merge at end (no-max softmax => partials just add).
__global__ __launch_bounds__(512, 6) void attn_k(const h16* __restrict__ Qh,
    const h16* __restrict__ Kh, const h16* __restrict__ Vth, h16* __restrict__ Oh)
{
    __shared__ h16 KVs[2][2][64*64];   // 32KB [buf][K|V]
    __shared__ h16 Ps[8][16*32];       // 8KB per-wave P (16 rows x 32 kv, slot-XOR)
    int id = blockIdx.x;
    int u = id >> 5;
    int qt = (u < 16) ? u : 47 - u;    // CU round-robin share sums to const work
    int bh = id & 31;
    int b = bh >> 4, h = bh & 15;
    int tid = threadIdx.x, w = tid >> 6, l = tid & 63;
    int g = w >> 2, wq = w & 3;
    int lq = l & 15, qq = l >> 4;
    int qstart = qt * 64;
    int q0w = qstart + wq * 16;
    h16* P = &Ps[w][0];
    int xs = (lq & 7) << 4;

    f16x8 qf[2];
#pragma unroll
    for (int kc = 0; kc < 2; ++kc)
        qf[kc] = *(const f16x8*)(Qh + (size_t)(b*2048 + q0w + lq)*1024 + h*64 + kc*32 + qq*8);

    int qrow = q0w + lq;
    int thr = (qrow < 64) ? 65 : qrow + 2;

    int cbs = ((tid & 7)*16) ^ (((tid >> 3) & 7) << 4);
    const char* ksrc = (const char*)(Kh + (size_t)b*2112*64) + (size_t)(tid >> 3)*128 + cbs;
    const char* vsrc = (const char*)(Vth + (size_t)b*64*2112) + (size_t)(tid >> 3)*4224 + cbs;

    f32x4 oacc[4] = {};
    float lrun = 0.f;

    int lastc = qstart + 65;
    if (lastc > 2049) lastc = 2049;
    int ntile = lastc/64 + 1;

    auto STAGE = [&](int buf, int kv0) {
        __builtin_amdgcn_global_load_lds(
            (const __attribute__((address_space(1))) unsigned int*)(ksrc + (size_t)kv0*128),
            (__attribute__((address_space(3))) unsigned int*)(&KVs[buf][0][w*512]), 16, 0, 0);
        __builtin_amdgcn_global_load_lds(
            (const __attribute__((address_space(1))) unsigned int*)(vsrc + (size_t)kv0*2),
            (__attribute__((address_space(3))) unsigned int*)(&KVs[buf][1][w*512]), 16, 0, 0);
    };

    STAGE(0, 0);
    int cur = 0;
    for (int t = 0; t < ntile; ++t) {
        int kv0 = t*64;
        int nxt = (t + 1 < ntile) ? t + 1 : t;
        STAGE(cur ^ 1, nxt*64);
        asm volatile("s_waitcnt vmcnt(2)" ::: "memory");
        __builtin_amdgcn_s_barrier();
        __builtin_amdgcn_sched_barrier(0);

        int kv0g = kv0 + g*32;
        bool active = (kv0g <= q0w + 17) || (q0w < 64 && kv0g < 66);
        if (active) {
            const char* Kl = (const char*)&KVs[cur][0][0];
            const char* Vl = (const char*)&KVs[cur][1][0];
            f32x4 s[2] = {};
#pragma unroll
            for (int kc = 0; kc < 2; ++kc) {
                int ko = (kc*64 + qq*16) ^ xs;
                f16x8 kf0 = *(const f16x8*)(Kl + ((g*2+0)*16 + lq)*128 + ko);
                f16x8 kf1 = *(const f16x8*)(Kl + ((g*2+1)*16 + lq)*128 + ko);
                s[0] = __builtin_amdgcn_mfma_f32_16x16x32_f16(kf0, qf[kc], s[0], 0, 0, 0);
                s[1] = __builtin_amdgcn_mfma_f32_16x16x32_f16(kf1, qf[kc], s[1], 0, 0, 0);
            }
            if (kv0g + 31 > q0w + 2) {
#pragma unroll
                for (int mt = 0; mt < 2; ++mt)
#pragma unroll
                    for (int i = 0; i < 4; ++i) {
                        int kv = kv0g + mt*16 + qq*4 + i;
                        if (kv > thr) s[mt][i] = -__builtin_inff();
                    }
            }
            float ps = 0.f;
#pragma unroll
            for (int mt = 0; mt < 2; ++mt)
#pragma unroll
                for (int i = 0; i < 4; ++i) {
                    float p = exp2f(s[mt][i]);
                    s[mt][i] = p; ps += p;
                }
            ps += __shfl_xor(ps, 16);
            ps += __shfl_xor(ps, 32);
            lrun += ps;
            // P write: row lq (64B), logical slot sw=mt*2+(qq>>1), phys slot = sw^(lq&3)
#pragma unroll
            for (int mt = 0; mt < 2; ++mt) {
                uint2 pk;
                pk.x = __builtin_bit_cast(unsigned int, __builtin_amdgcn_cvt_pkrtz(s[mt][0], s[mt][1]));
                pk.y = __builtin_bit_cast(unsigned int, __builtin_amdgcn_cvt_pkrtz(s[mt][2], s[mt][3]));
                *(uint2*)((char*)P + lq*64 + (((mt*2 + (qq>>1)) ^ (lq&3)) << 4) + (qq&1)*8) = pk;
            }
            f16x8 pf = *(const f16x8*)((const char*)P + lq*64 + ((qq ^ (lq&3)) << 4));
            int kov = (g*64 + qq*16) ^ xs;
#pragma unroll
            for (int dm = 0; dm < 4; ++dm) {
                f16x8 vf = *(const f16x8*)(Vl + (dm*16 + lq)*128 + kov);
                oacc[dm] = __builtin_amdgcn_mfma_f32_16x16x32_f16(vf, pf, oacc[dm], 0, 0, 0);
            }
        }
        __builtin_amdgcn_sched_barrier(0);
        __builtin_amdgcn_s_barrier();
        cur ^= 1;
    }
    asm volatile("s_waitcnt vmcnt(0)" ::: "memory");   // drain last redundant prefetch
    __syncthreads();                                    // KVs safe to reuse as merge area

    float* Om = (float*)&KVs[0][0][0];   // [wq][16 q][64 d] f32 = 16KB
    float* Lm = (float*)&Ps[0][0];       // [wq][16 q]
    if (g == 1) {
#pragma unroll
        for (int dm = 0; dm < 4; ++dm)
            *(f32x4*)(Om + wq*1024 + lq*64 + dm*16 + qq*4) = oacc[dm];
        if (qq == 0) Lm[wq*16 + lq] = lrun;
    }
    __syncthreads();
    if (g == 0) {
        float ltot = lrun + Lm[wq*16 + lq];
        float inv = 1.f / ltot;
#pragma unroll
        for (int dm = 0; dm < 4; ++dm) {
            f32x4 po = *(const f32x4*)(Om + wq*1024 + lq*64 + dm*16 + qq*4);
            f16x4 ov;
#pragma unroll
            for (int i = 0; i < 4; ++i) ov[i] = (h16)((oacc[dm][i] + po[i]) * inv);
            *(f16x4*)(Oh + (size_t)(b*2048 + q0w + lq)*1024 + h*64 + dm*16 + qq*4) = ov;
        }
    }
}

extern "C" void kernel_launch(void* const* d_in, const int* in_sizes, int n_in,
                              void* d_out, int out_size, void* d_ws, size_t ws_size,
                              hipStream_t stream)
{
    const float* x      = (const float*)d_in[0];
    const float* gamma  = (const float*)d_in[1];
    const float* Wq     = (const float*)d_in[2];
    const float* Wkv    = (const float*)d_in[3];
    const float* qscale = (const float*)d_in[4];
    const float* kscale = (const float*)d_in[5];
    const float* nkv    = (const float*)d_in[6];
    const float* Wout   = (const float*)d_in[7];
    float* out = (float*)d_out;
    char* ws = (char*)d_ws;

    h16* xh   = (h16*)(ws);                     // 8388608
    h16* Qh   = (h16*)(ws + 8388608);           // 8388608
    h16* Oh   = (h16*)(ws + 16777216);          // 8388608
    h16* W1t  = (h16*)(ws + 25165824);          // 2359296
    h16* Wot  = (h16*)(ws + 27525120);          // 2097152
    h16* Kh   = (h16*)(ws + 29622272);          // 540672
    h16* Vth  = (h16*)(ws + 30162944);          // 540672
    float* cq = (float*)(ws + 30703616);        // 4096
    float* mu = (float*)(ws + 30707712);        // 16384
    float* rr = (float*)(ws + 30724096);        // 16384

    hipMemsetAsync(cq, 0, 4096, stream);
    prep_w<<<dim3(16, 34), 256, 0, stream>>>(Wq, Wkv, Wout, gamma, W1t, Wot, cq);
    stats_k<<<dim3(1024), 256, 0, stream>>>(x, mu, rr, xh);
    null_k<<<dim3(8), 256, 0, stream>>>(nkv, kscale, Kh, Vth);
    gemm_k<0><<<dim3(9, 32), 256, 0, stream>>>(xh, W1t, mu, rr, cq, qscale, kscale, Qh, Kh, Vth, out);
    attn_k<<<dim3(1024), 512, 0, stream>>>(Qh, Kh, Vth, Oh);
    gemm_k<1><<<dim3(8, 32), 256, 0, stream>>>(Oh, Wot, mu, rr, cq, qscale, kscale, Qh, Kh, Vth, out);
}

// Round 8
// 100.699 us; speedup vs baseline: 2.1685x; 1.1401x over previous
//
#include <hip/hip_runtime.h>

typedef _Float16 h16;
typedef _Float16 f16x8 __attribute__((ext_vector_type(8)));
typedef _Float16 f16x4 __attribute__((ext_vector_type(4)));
typedef float f32x4 __attribute__((ext_vector_type(4)));

#define KSCALE_FOLD 11.541560327111707f   // 8 * log2(e), folded into Kh

// ---------------- prep: weight transposes to [N][K] fp16, + cq colsum fused ----------------
__global__ __launch_bounds__(256) void prep_w(const float* __restrict__ Wq,
    const float* __restrict__ Wkv, const float* __restrict__ Wout,
    const float* __restrict__ gamma, h16* __restrict__ W1t, h16* __restrict__ Wot,
    float* __restrict__ cq)
{
    __shared__ float ts[64][65];
    int bx = blockIdx.x, by = blockIdx.y;
    int c = threadIdx.x & 63, rc = threadIdx.x >> 6;
    const float* src; int ld, scol, drow0; h16* dst; bool useg = false;
    if (by < 16)      { src = Wq;   ld = 1024; scol = by*64;       dst = W1t; drow0 = scol;        useg = true; }
    else if (by < 18) { src = Wkv;  ld = 128;  scol = (by-16)*64;  dst = W1t; drow0 = 1024 + scol; }
    else              { src = Wout; ld = 1024; scol = (by-18)*64;  dst = Wot; drow0 = scol; }
    float part = 0.f;
#pragma unroll
    for (int i = 0; i < 16; ++i) {
        int r = rc*16 + i;
        float v = src[(size_t)(bx*64 + r)*ld + scol + c];
        if (useg) v *= gamma[bx*64 + r];
        part += v;
        ts[r][c] = v;
    }
    if (useg) atomicAdd(&cq[scol + c], part);
    __syncthreads();
#pragma unroll
    for (int i = 0; i < 16; ++i) {
        int r = rc*16 + i;
        dst[(size_t)(drow0 + r)*1024 + bx*64 + c] = (h16)ts[c][r];
    }
}

// per-row mean + rsqrt(var+eps), and x -> fp16
__global__ __launch_bounds__(256) void stats_k(const float* __restrict__ x,
    float* __restrict__ mu, float* __restrict__ rr, h16* __restrict__ xh)
{
    int w = threadIdx.x >> 6, l = threadIdx.x & 63;
    int row = blockIdx.x*4 + w;
    const float* xr = x + (size_t)row*1024;
    float s = 0.f, ss = 0.f;
    float4 v[4];
#pragma unroll
    for (int i = 0; i < 4; ++i) {
        v[i] = *(const float4*)(xr + i*256 + l*4);
        s  += v[i].x + v[i].y + v[i].z + v[i].w;
        ss += v[i].x*v[i].x + v[i].y*v[i].y + v[i].z*v[i].z + v[i].w*v[i].w;
    }
#pragma unroll
    for (int m = 1; m < 64; m <<= 1) { s += __shfl_xor(s, m); ss += __shfl_xor(ss, m); }
    float m_ = s * (1.f/1024.f);
    float var = ss * (1.f/1024.f) - m_*m_;
    float r_ = rsqrtf(var + 1e-5f);
    if (l == 0) { mu[row] = m_; rr[row] = r_; }
    h16* xo = xh + (size_t)row*1024;
#pragma unroll
    for (int i = 0; i < 4; ++i) {
        f16x4 hv = { (h16)v[i].x, (h16)v[i].y, (h16)v[i].z, (h16)v[i].w };
        *(f16x4*)(xo + i*256 + l*4) = hv;
    }
}

// null kv rows (l2norm'd k * k_scale * 8*log2e; raw v), zero the padding tail
__global__ __launch_bounds__(256) void null_k(const float* __restrict__ nkv,
    const float* __restrict__ kscale, h16* __restrict__ Kh, h16* __restrict__ Vth)
{
    int tid = threadIdx.x;
    if (blockIdx.x == 0 && tid < 128) {
        int t = tid >> 6, d = tid & 63;
        float kv = nkv[(0*2 + t)*64 + d];
        float ss = kv*kv;
#pragma unroll
        for (int m = 1; m < 64; m <<= 1) ss += __shfl_xor(ss, m);
        float inv = 1.f / fmaxf(sqrtf(ss), 1e-12f);
        h16 kvh = (h16)(kv * inv * kscale[d] * KSCALE_FOLD);
        Kh[(size_t)(0*2112 + t)*64 + d] = kvh;
        Kh[(size_t)(1*2112 + t)*64 + d] = kvh;
        float nv = nkv[(2 + t)*64 + d];
        Vth[(size_t)(0*64 + d)*2112 + t] = (h16)nv;
        Vth[(size_t)(1*64 + d)*2112 + t] = (h16)nv;
    }
    for (int idx = blockIdx.x*256 + tid; idx < 2*62*64; idx += 2048) {
        int b = idx / (62*64), rem = idx % (62*64);
        int j = 2050 + rem/64, d = rem & 63;
        Kh[((size_t)b*2112 + j)*64 + d] = (h16)0.f;
        Vth[((size_t)b*64 + d)*2112 + j] = (h16)0.f;
    }
}

// ---------------- GEMM (128x64 tile, BK=64, 4 waves M-stacked, dbuf gl_lds + XOR swizzle) ----------------
// MODE 0: A=xh[4096][1024], B=W1t[1152][1024]; bx<16 -> q(head bx), bx==16 -> k, bx==17 -> v
// MODE 1: A=Oh[4096][1024], B=Wot[1024][1024]; fp32 store
template<int MODE>
__global__ __launch_bounds__(256) void gemm_k(
    const h16* __restrict__ A, const h16* __restrict__ B,
    const float* __restrict__ mu, const float* __restrict__ rr, const float* __restrict__ cq,
    const float* __restrict__ qscale, const float* __restrict__ kscale,
    h16* __restrict__ Qh, h16* __restrict__ Kh, h16* __restrict__ Vth, float* __restrict__ outp)
{
    __shared__ h16 As[2][128*64];   // 32KB
    __shared__ h16 Bs[2][64*64];    // 16KB
    int tid = threadIdx.x;
    int w = tid >> 6, l = tid & 63;
    int lq = l & 15, qq = l >> 4;
    int arow0 = blockIdx.y*128, bcol0 = blockIdx.x*64;
    const int K = 1024;
    f32x4 acc[2][4] = {};

    auto STAGE = [&](int buf, int kt) {
#pragma unroll
        for (int i = 0; i < 4; ++i) {            // A: 128x64 = 1024 slots
            int s = i*256 + tid;
            int row = s >> 3;
            int cb = ((s & 7)*16) ^ ((row & 7) << 4);
            const char* asrc = (const char*)(A + (size_t)(arow0 + row)*K + kt) + cb;
            __builtin_amdgcn_global_load_lds(
                (const __attribute__((address_space(1))) unsigned int*)asrc,
                (__attribute__((address_space(3))) unsigned int*)((char*)&As[buf][0] + s*16), 16, 0, 0);
        }
#pragma unroll
        for (int i = 0; i < 2; ++i) {            // B: 64x64 = 512 slots
            int s = i*256 + tid;
            int row = s >> 3;
            int cb = ((s & 7)*16) ^ ((row & 7) << 4);
            const char* bsrc = (const char*)(B + (size_t)(bcol0 + row)*K + kt) + cb;
            __builtin_amdgcn_global_load_lds(
                (const __attribute__((address_space(1))) unsigned int*)bsrc,
                (__attribute__((address_space(3))) unsigned int*)((char*)&Bs[buf][0] + s*16), 16, 0, 0);
        }
    };

    STAGE(0, 0);
    int cur = 0;
    for (int kt = 0; kt < K; kt += 64) {
        int nkt = (kt + 64 < K) ? kt + 64 : kt;
        STAGE(cur ^ 1, nkt);
        asm volatile("s_waitcnt vmcnt(6)" ::: "memory");
        __builtin_amdgcn_s_barrier();
        __builtin_amdgcn_sched_barrier(0);
        const char* Ab = (const char*)&As[cur][0];
        const char* Bb = (const char*)&Bs[cur][0];
#pragma unroll
        for (int kc = 0; kc < 2; ++kc) {
            int cb = (kc*64 + qq*16) ^ ((lq & 7) << 4);
            f16x8 af[2], bf[4];
#pragma unroll
            for (int mt = 0; mt < 2; ++mt)
                af[mt] = *(const f16x8*)(Ab + (w*32 + mt*16 + lq)*128 + cb);
#pragma unroll
            for (int nt = 0; nt < 4; ++nt)
                bf[nt] = *(const f16x8*)(Bb + (nt*16 + lq)*128 + cb);
#pragma unroll
            for (int mt = 0; mt < 2; ++mt)
#pragma unroll
                for (int nt = 0; nt < 4; ++nt)
                    acc[mt][nt] = __builtin_amdgcn_mfma_f32_16x16x32_f16(af[mt], bf[nt], acc[mt][nt], 0, 0, 0);
        }
        __builtin_amdgcn_sched_barrier(0);
        __builtin_amdgcn_s_barrier();
        cur ^= 1;
    }
    asm volatile("s_waitcnt vmcnt(0)" ::: "memory");

    int wrow0 = arow0 + w*32;
    int bx = blockIdx.x;
    if (MODE == 1) {
#pragma unroll
        for (int mt = 0; mt < 2; ++mt)
#pragma unroll
            for (int nt = 0; nt < 4; ++nt)
#pragma unroll
                for (int i = 0; i < 4; ++i)
                    outp[(size_t)(wrow0 + mt*16 + qq*4 + i)*1024 + bcol0 + nt*16 + lq] = acc[mt][nt][i];
        return;
    }
    if (bx < 16) {          // q columns: LN-fold + l2norm * q_scale (head = bx)
        float cqv[4], qs[4];
#pragma unroll
        for (int nt = 0; nt < 4; ++nt) {
            cqv[nt] = cq[bcol0 + nt*16 + lq];
            qs[nt] = qscale[nt*16 + lq];
        }
#pragma unroll
        for (int mt = 0; mt < 2; ++mt) {
            float muv[4], rv[4], ssq[4], qv[4][4];
#pragma unroll
            for (int i = 0; i < 4; ++i) {
                int row = wrow0 + mt*16 + qq*4 + i;
                muv[i] = mu[row]; rv[i] = rr[row]; ssq[i] = 0.f;
            }
#pragma unroll
            for (int nt = 0; nt < 4; ++nt)
#pragma unroll
                for (int i = 0; i < 4; ++i) {
                    float q = rv[i]*(acc[mt][nt][i] - muv[i]*cqv[nt]);
                    qv[nt][i] = q; ssq[i] += q*q;
                }
#pragma unroll
            for (int i = 0; i < 4; ++i) {
                float s2 = ssq[i];
                s2 += __shfl_xor(s2, 1); s2 += __shfl_xor(s2, 2);
                s2 += __shfl_xor(s2, 4); s2 += __shfl_xor(s2, 8);
                ssq[i] = 1.f / fmaxf(sqrtf(s2), 1e-12f);
            }
#pragma unroll
            for (int nt = 0; nt < 4; ++nt)
#pragma unroll
                for (int i = 0; i < 4; ++i) {
                    int row = wrow0 + mt*16 + qq*4 + i;
                    Qh[(size_t)row*1024 + bcol0 + nt*16 + lq] = (h16)(qv[nt][i]*ssq[i]*qs[nt]);
                }
        }
    } else if (bx == 16) {  // k: l2norm * k_scale * 8log2e
        float ks[4];
#pragma unroll
        for (int nt = 0; nt < 4; ++nt) ks[nt] = kscale[nt*16 + lq] * KSCALE_FOLD;
#pragma unroll
        for (int mt = 0; mt < 2; ++mt) {
            float ssq[4] = {0.f, 0.f, 0.f, 0.f};
#pragma unroll
            for (int nt = 0; nt < 4; ++nt)
#pragma unroll
                for (int i = 0; i < 4; ++i) ssq[i] += acc[mt][nt][i]*acc[mt][nt][i];
#pragma unroll
            for (int i = 0; i < 4; ++i) {
                float s2 = ssq[i];
                s2 += __shfl_xor(s2, 1); s2 += __shfl_xor(s2, 2);
                s2 += __shfl_xor(s2, 4); s2 += __shfl_xor(s2, 8);
                ssq[i] = 1.f / fmaxf(sqrtf(s2), 1e-12f);
            }
#pragma unroll
            for (int nt = 0; nt < 4; ++nt)
#pragma unroll
                for (int i = 0; i < 4; ++i) {
                    int row = wrow0 + mt*16 + qq*4 + i;
                    int b = row >> 11, ii = row & 2047;
                    Kh[((size_t)b*2112 + 2 + ii)*64 + nt*16 + lq] = (h16)(acc[mt][nt][i]*ssq[i]*ks[nt]);
                }
        }
    } else {                // v: transposed store
#pragma unroll
        for (int mt = 0; mt < 2; ++mt)
#pragma unroll
            for (int nt = 0; nt < 4; ++nt)
#pragma unroll
                for (int i = 0; i < 4; ++i) {
                    int row = wrow0 + mt*16 + qq*4 + i;
                    int b = row >> 11, ii = row & 2047;
                    Vth[((size_t)b*64 + nt*16 + lq)*2112 + 2 + ii] = (h16)acc[mt][nt][i];
                }
    }
}

// ---------------- attention: 8-wave kv-split staticmax exp2 flash ----------------
// block = 64 q rows; waves w and w+4 share rows, split each kv tile into halves.
// P geometry: 128B rows + 16B-slot XOR (2-way max = free).
__global__ __launch_bounds__(512) void attn_k(const h16* __restrict__ Qh,
    const h16* __restrict__ Kh, const h16* __restrict__ Vth, h16* __restrict__ Oh)
{
    __shared__ h16 KVs[2][2][64*64];   // 32KB [buf][K|V]
    __shared__ h16 Ps[8][16*64];       // 16KB per-wave P (128B rows)
    int id = blockIdx.x;
    int u = id >> 5;
    int qt = (u < 16) ? u : 47 - u;    // CU round-robin share sums to const work
    int bh = id & 31;
    int b = bh >> 4, h = bh & 15;
    int tid = threadIdx.x, w = tid >> 6, l = tid & 63;
    int g = w >> 2, wq = w & 3;
    int lq = l & 15, qq = l >> 4;
    int qstart = qt * 64;
    int q0w = qstart + wq * 16;
    h16* P = &Ps[w][0];
    int xs = (lq & 7) << 4;

    f16x8 qf[2];
#pragma unroll
    for (int kc = 0; kc < 2; ++kc)
        qf[kc] = *(const f16x8*)(Qh + (size_t)(b*2048 + q0w + lq)*1024 + h*64 + kc*32 + qq*8);

    int qrow = q0w + lq;
    int thr = (qrow < 64) ? 65 : qrow + 2;

    int cbs = ((tid & 7)*16) ^ (((tid >> 3) & 7) << 4);
    const char* ksrc = (const char*)(Kh + (size_t)b*2112*64) + (size_t)(tid >> 3)*128 + cbs;
    const char* vsrc = (const char*)(Vth + (size_t)b*64*2112) + (size_t)(tid >> 3)*4224 + cbs;

    f32x4 oacc[4] = {};
    float lrun = 0.f;

    int lastc = qstart + 65;
    if (lastc > 2049) lastc = 2049;
    int ntile = lastc/64 + 1;

    auto STAGE = [&](int buf, int kv0) {
        __builtin_amdgcn_global_load_lds(
            (const __attribute__((address_space(1))) unsigned int*)(ksrc + (size_t)kv0*128),
            (__attribute__((address_space(3))) unsigned int*)(&KVs[buf][0][w*512]), 16, 0, 0);
        __builtin_amdgcn_global_load_lds(
            (const __attribute__((address_space(1))) unsigned int*)(vsrc + (size_t)kv0*2),
            (__attribute__((address_space(3))) unsigned int*)(&KVs[buf][1][w*512]), 16, 0, 0);
    };

    STAGE(0, 0);
    int cur = 0;
    for (int t = 0; t < ntile; ++t) {
        int kv0 = t*64;
        int nxt = (t + 1 < ntile) ? t + 1 : t;
        STAGE(cur ^ 1, nxt*64);
        asm volatile("s_waitcnt vmcnt(2)" ::: "memory");
        __builtin_amdgcn_s_barrier();
        __builtin_amdgcn_sched_barrier(0);

        int kv0g = kv0 + g*32;
        bool active = (kv0g <= q0w + 17) || (q0w < 64 && kv0g < 66);
        if (active) {
            const char* Kl = (const char*)&KVs[cur][0][0];
            const char* Vl = (const char*)&KVs[cur][1][0];
            f32x4 s[2] = {};
#pragma unroll
            for (int kc = 0; kc < 2; ++kc) {
                int ko = (kc*64 + qq*16) ^ xs;
                f16x8 kf0 = *(const f16x8*)(Kl + ((g*2+0)*16 + lq)*128 + ko);
                f16x8 kf1 = *(const f16x8*)(Kl + ((g*2+1)*16 + lq)*128 + ko);
                s[0] = __builtin_amdgcn_mfma_f32_16x16x32_f16(kf0, qf[kc], s[0], 0, 0, 0);
                s[1] = __builtin_amdgcn_mfma_f32_16x16x32_f16(kf1, qf[kc], s[1], 0, 0, 0);
            }
            if (kv0g + 31 > q0w + 2) {
#pragma unroll
                for (int mt = 0; mt < 2; ++mt)
#pragma unroll
                    for (int i = 0; i < 4; ++i) {
                        int kv = kv0g + mt*16 + qq*4 + i;
                        if (kv > thr) s[mt][i] = -__builtin_inff();
                    }
            }
            float ps = 0.f;
#pragma unroll
            for (int mt = 0; mt < 2; ++mt)
#pragma unroll
                for (int i = 0; i < 4; ++i) {
                    float p = exp2f(s[mt][i]);
                    s[mt][i] = p; ps += p;
                }
            ps += __shfl_xor(ps, 16);
            ps += __shfl_xor(ps, 32);
            lrun += ps;
            // P write: 128B rows, kv*2 byte col ^ xs (16B-slot XOR)
#pragma unroll
            for (int mt = 0; mt < 2; ++mt) {
                uint2 pk;
                pk.x = __builtin_bit_cast(unsigned int, __builtin_amdgcn_cvt_pkrtz(s[mt][0], s[mt][1]));
                pk.y = __builtin_bit_cast(unsigned int, __builtin_amdgcn_cvt_pkrtz(s[mt][2], s[mt][3]));
                *(uint2*)((char*)P + lq*128 + ((mt*32 + qq*8) ^ xs)) = pk;
            }
            f16x8 pf = *(const f16x8*)((const char*)P + lq*128 + ((qq*16) ^ xs));
            int kov = (g*64 + qq*16) ^ xs;
#pragma unroll
            for (int dm = 0; dm < 4; ++dm) {
                f16x8 vf = *(const f16x8*)(Vl + (dm*16 + lq)*128 + kov);
                oacc[dm] = __builtin_amdgcn_mfma_f32_16x16x32_f16(vf, pf, oacc[dm], 0, 0, 0);
            }
        }
        __builtin_amdgcn_sched_barrier(0);
        __builtin_amdgcn_s_barrier();
        cur ^= 1;
    }
    asm volatile("s_waitcnt vmcnt(0)" ::: "memory");
    __syncthreads();   // KVs/Ps safe to reuse as merge area

    float* Om = (float*)&KVs[0][0][0];   // [wq][16 q][64 d] f32 = 16KB
    float* Lm = (float*)&Ps[0][0];       // [wq][16 q]
    if (g == 1) {
#pragma unroll
        for (int dm = 0; dm < 4; ++dm)
            *(f32x4*)(Om + wq*1024 + lq*64 + dm*16 + qq*4) = oacc[dm];
        if (qq == 0) Lm[wq*16 + lq] = lrun;
    }
    __syncthreads();
    if (g == 0) {
        float ltot = lrun + Lm[wq*16 + lq];
        float inv = 1.f / ltot;
#pragma unroll
        for (int dm = 0; dm < 4; ++dm) {
            f32x4 po = *(const f32x4*)(Om + wq*1024 + lq*64 + dm*16 + qq*4);
            f16x4 ov;
#pragma unroll
            for (int i = 0; i < 4; ++i) ov[i] = (h16)((oacc[dm][i] + po[i]) * inv);
            *(f16x4*)(Oh + (size_t)(b*2048 + q0w + lq)*1024 + h*64 + dm*16 + qq*4) = ov;
        }
    }
}

extern "C" void kernel_launch(void* const* d_in, const int* in_sizes, int n_in,
                              void* d_out, int out_size, void* d_ws, size_t ws_size,
                              hipStream_t stream)
{
    const float* x      = (const float*)d_in[0];
    const float* gamma  = (const float*)d_in[1];
    const float* Wq     = (const float*)d_in[2];
    const float* Wkv    = (const float*)d_in[3];
    const float* qscale = (const float*)d_in[4];
    const float* kscale = (const float*)d_in[5];
    const float* nkv    = (const float*)d_in[6];
    const float* Wout   = (const float*)d_in[7];
    float* out = (float*)d_out;
    char* ws = (char*)d_ws;

    h16* xh   = (h16*)(ws);                     // 8388608
    h16* Qh   = (h16*)(ws + 8388608);           // 8388608
    h16* Oh   = (h16*)(ws + 16777216);          // 8388608
    h16* W1t  = (h16*)(ws + 25165824);          // 2359296
    h16* Wot  = (h16*)(ws + 27525120);          // 2097152
    h16* Kh   = (h16*)(ws + 29622272);          // 540672
    h16* Vth  = (h16*)(ws + 30162944);          // 540672
    float* cq = (float*)(ws + 30703616);        // 4096
    float* mu = (float*)(ws + 30707712);        // 16384
    float* rr = (float*)(ws + 30724096);        // 16384

    hipMemsetAsync(cq, 0, 4096, stream);
    prep_w<<<dim3(16, 34), 256, 0, stream>>>(Wq, Wkv, Wout, gamma, W1t, Wot, cq);
    stats_k<<<dim3(1024), 256, 0, stream>>>(x, mu, rr, xh);
    null_k<<<dim3(8), 256, 0, stream>>>(nkv, kscale, Kh, Vth);
    gemm_k<0><<<dim3(18, 32), 256, 0, stream>>>(xh, W1t, mu, rr, cq, qscale, kscale, Qh, Kh, Vth, out);
    attn_k<<<dim3(1024), 512, 0, stream>>>(Qh, Kh, Vth, Oh);
    gemm_k<1><<<dim3(16, 32), 256, 0, stream>>>(Oh, Wot, mu, rr, cq, qscale, kscale, Qh, Kh, Vth, out);
}